// Round 2
// baseline (979.730 us; speedup 1.0000x reference)
//
#include <hip/hip_runtime.h>

typedef unsigned short u16;
typedef unsigned int   u32;

#define HW 4096
#define NC 128

__device__ __forceinline__ float bf2f(u16 h){ return __uint_as_float(((u32)h) << 16); }
__device__ __forceinline__ u16 f2bf(float f){
    u32 u = __float_as_uint(f);
    return (u16)((u + 0x7fffu + ((u >> 16) & 1u)) >> 16);
}
__device__ __forceinline__ float bf_lo(u32 u){ return __uint_as_float(u << 16); }
__device__ __forceinline__ float bf_hi(u32 u){ return __uint_as_float(u & 0xffff0000u); }
__device__ __forceinline__ void unpack8(uint4 u, float* v){
    v[0]=bf_lo(u.x); v[1]=bf_hi(u.x); v[2]=bf_lo(u.y); v[3]=bf_hi(u.y);
    v[4]=bf_lo(u.z); v[5]=bf_hi(u.z); v[6]=bf_lo(u.w); v[7]=bf_hi(u.w);
}

// ---------------- K1: GroupNorm stats. grid=32 (b*8+g), block=256 ----------------
// Each group's 16ch x 4096 = 65536 fp32 elems are contiguous.
__global__ __launch_bounds__(256) void gn_stats_kernel(const float* __restrict__ x,
                                                       float* __restrict__ stats){
    int bg = blockIdx.x;
    const float4* p = (const float4*)(x + (size_t)bg * 65536);
    float s = 0.f, ss = 0.f;
    for (int i = threadIdx.x; i < 16384; i += 256){
        float4 u = p[i];
        s  += u.x + u.y + u.z + u.w;
        ss += u.x*u.x + u.y*u.y + u.z*u.z + u.w*u.w;
    }
    #pragma unroll
    for (int off = 32; off > 0; off >>= 1){
        s  += __shfl_xor(s,  off);
        ss += __shfl_xor(ss, off);
    }
    __shared__ float rs[4], rss[4];
    int wid = threadIdx.x >> 6;
    if ((threadIdx.x & 63) == 0){ rs[wid] = s; rss[wid] = ss; }
    __syncthreads();
    if (threadIdx.x == 0){
        float S = rs[0]+rs[1]+rs[2]+rs[3];
        float SS = rss[0]+rss[1]+rss[2]+rss[3];
        float mean = S * (1.f/65536.f);
        float var  = SS * (1.f/65536.f) - mean*mean;
        stats[bg*2]   = mean;
        stats[bg*2+1] = rsqrtf(var + 1e-5f);
    }
}

// ---------------- K2: fused GN-apply + QKV GEMM ----------------
// grid (64 n-tiles, 6 o-tiles, 4 b), block 256. out tile 64o x 64n. bf16 out.
__global__ __launch_bounds__(256) void qkv_kernel(const float* __restrict__ x,
                                                  const float* __restrict__ stats,
                                                  const float* __restrict__ gamma,
                                                  const float* __restrict__ beta,
                                                  const float* __restrict__ w,
                                                  const float* __restrict__ bias,
                                                  u16* __restrict__ qkv){
    int n0 = blockIdx.x * 64;
    int o0 = blockIdx.y * 64;
    int b  = blockIdx.z;
    __shared__ float Wt[64][128];   // [o][c]  (read wave-uniform b128 -> broadcast)
    __shared__ float Xt[128][64];   // [c][n]  (lane reads 2-way, free)
    int t = threadIdx.x;

    // W tile: 64 rows x 128 c fp32 = 2048 float4
    const float4* w4 = (const float4*)(w + (size_t)o0 * NC);
    #pragma unroll
    for (int i = 0; i < 8; i++){
        int f = t + i*256;
        int o = f >> 5, c4 = f & 31;
        *(float4*)&Wt[o][c4*4] = w4[f];
    }
    // X tile with GN applied: 128c x 64n fp32 = 2048 float4
    #pragma unroll
    for (int i = 0; i < 8; i++){
        int f = t + i*256;
        int c = f >> 4, m4 = f & 15;
        float4 u = *(const float4*)(x + ((size_t)b*NC + c)*HW + n0 + m4*4);
        float mean = stats[(b*8 + (c>>4))*2];
        float rstd = stats[(b*8 + (c>>4))*2 + 1];
        float ga = gamma[c] * rstd;
        float be = beta[c] - mean * ga;
        u.x = u.x*ga + be; u.y = u.y*ga + be; u.z = u.z*ga + be; u.w = u.w*ga + be;
        *(float4*)&Xt[c][m4*4] = u;
    }
    __syncthreads();

    int lane = t & 63, wid = t >> 6;   // wave owns 16 o-rows, lane = n
    float acc[16] = {};
    for (int c4 = 0; c4 < 32; c4++){
        float xv[4];
        #pragma unroll
        for (int k = 0; k < 4; k++) xv[k] = Xt[c4*4+k][lane];
        #pragma unroll
        for (int i = 0; i < 16; i++){
            float4 wv = *(float4*)&Wt[wid*16 + i][c4*4];
            acc[i] += wv.x*xv[0] + wv.y*xv[1] + wv.z*xv[2] + wv.w*xv[3];
        }
    }
    #pragma unroll
    for (int i = 0; i < 16; i++){
        int o = o0 + wid*16 + i;
        qkv[((size_t)b*384 + o)*HW + n0 + lane] = f2bf(acc[i] + bias[o]);
    }
}

// ---------------- K3: flash attention (bf16 in/out intermediates) ----------------
// grid (128 q-tiles, 4 b), block 256. TQ=32, TK=64.
__global__ __launch_bounds__(256) void attn_kernel(const u16* __restrict__ qkv,
                                                   u16* __restrict__ ao){
    int b  = blockIdx.y;
    int q0 = blockIdx.x * 32;
    __shared__ float Qs[128][32];    // [c][r]
    __shared__ float KVs[128][68];   // K then V, [c][m], pad 68
    __shared__ float Ps[32][65];     // [r][m], pad 65
    __shared__ float alphas[32];
    __shared__ float lsum[32];
    int t = threadIdx.x;
    int lane = t & 63, wid = t >> 6;       // softmax org: wave wid owns rows wid*8..+7
    int tr = t & 7, tc = t >> 3;           // PV org: rows tr+8i, cols tc+32j
    const float scale = 0.08838834764831845f;  // 1/sqrt(128)
    const u16* qkvb = qkv + (size_t)b * 384 * HW;

    // Q tile: 128c x 32r bf16 = 512 uint4
    #pragma unroll
    for (int i = 0; i < 2; i++){
        int f = t + i*256;
        int c = f >> 2, r8 = f & 3;
        uint4 u = *(const uint4*)(qkvb + (size_t)c*HW + q0 + r8*8);
        float v[8]; unpack8(u, v);
        *(float4*)&Qs[c][r8*8]   = make_float4(v[0],v[1],v[2],v[3]);
        *(float4*)&Qs[c][r8*8+4] = make_float4(v[4],v[5],v[6],v[7]);
    }

    float m_i[8], l_i[8];
    #pragma unroll
    for (int j = 0; j < 8; j++){ m_i[j] = -1e30f; l_i[j] = 0.f; }
    float O[4][4] = {};

    for (int k0 = 0; k0 < HW; k0 += 64){
        __syncthreads();   // KVs free (prev PV done)
        // K tile: 128c x 64m bf16 = 1024 uint4
        #pragma unroll
        for (int i = 0; i < 4; i++){
            int f = t + i*256;
            int c = f >> 3, m8 = f & 7;
            uint4 u = *(const uint4*)(qkvb + (size_t)(128+c)*HW + k0 + m8*8);
            float v[8]; unpack8(u, v);
            *(float4*)&KVs[c][m8*8]   = make_float4(v[0],v[1],v[2],v[3]);
            *(float4*)&KVs[c][m8*8+4] = make_float4(v[4],v[5],v[6],v[7]);
        }
        __syncthreads();
        // S: 8 rows per wave, lane = key m
        float s[8];
        #pragma unroll
        for (int j = 0; j < 8; j++) s[j] = 0.f;
        for (int c = 0; c < 128; c++){
            float kv = KVs[c][lane];
            float4 qa = *(float4*)&Qs[c][wid*8];
            float4 qc = *(float4*)&Qs[c][wid*8+4];
            s[0] += qa.x*kv; s[1] += qa.y*kv; s[2] += qa.z*kv; s[3] += qa.w*kv;
            s[4] += qc.x*kv; s[5] += qc.y*kv; s[6] += qc.z*kv; s[7] += qc.w*kv;
        }
        // online softmax
        #pragma unroll
        for (int j = 0; j < 8; j++){
            float sj = s[j] * scale;
            float mx = sj;
            #pragma unroll
            for (int off = 32; off > 0; off >>= 1) mx = fmaxf(mx, __shfl_xor(mx, off));
            float mnew = fmaxf(m_i[j], mx);
            float p = __expf(sj - mnew);
            float rsum = p;
            #pragma unroll
            for (int off = 32; off > 0; off >>= 1) rsum += __shfl_xor(rsum, off);
            float alpha = __expf(m_i[j] - mnew);
            l_i[j] = l_i[j]*alpha + rsum;
            m_i[j] = mnew;
            Ps[wid*8 + j][lane] = p;
            if (lane == 0) alphas[wid*8 + j] = alpha;
        }
        __syncthreads();   // softmax done: KVs reusable, Ps/alphas visible
        // V tile into KVs
        #pragma unroll
        for (int i = 0; i < 4; i++){
            int f = t + i*256;
            int c = f >> 3, m8 = f & 7;
            uint4 u = *(const uint4*)(qkvb + (size_t)(256+c)*HW + k0 + m8*8);
            float v[8]; unpack8(u, v);
            *(float4*)&KVs[c][m8*8]   = make_float4(v[0],v[1],v[2],v[3]);
            *(float4*)&KVs[c][m8*8+4] = make_float4(v[4],v[5],v[6],v[7]);
        }
        // rescale O while V loads are in flight
        float av[4];
        #pragma unroll
        for (int i = 0; i < 4; i++) av[i] = alphas[tr + i*8];
        #pragma unroll
        for (int i = 0; i < 4; i++)
            #pragma unroll
            for (int j = 0; j < 4; j++) O[i][j] *= av[i];
        __syncthreads();
        // PV: outer product, thread = 4 rows x 4 chans
        for (int m = 0; m < 64; m++){
            float pv[4], vv[4];
            #pragma unroll
            for (int i = 0; i < 4; i++) pv[i] = Ps[tr + i*8][m];
            #pragma unroll
            for (int j = 0; j < 4; j++) vv[j] = KVs[tc + j*32][m];
            #pragma unroll
            for (int i = 0; i < 4; i++)
                #pragma unroll
                for (int j = 0; j < 4; j++) O[i][j] += pv[i]*vv[j];
        }
    }
    // hand l from softmax org to PV org
    if (lane == 0)
        #pragma unroll
        for (int j = 0; j < 8; j++) lsum[wid*8 + j] = l_i[j];
    __syncthreads();
    float linv[4];
    #pragma unroll
    for (int i = 0; i < 4; i++) linv[i] = 1.f / lsum[tr + i*8];
    u16* aob = ao + ((size_t)b*HW + q0) * NC;
    #pragma unroll
    for (int i = 0; i < 4; i++)
        #pragma unroll
        for (int j = 0; j < 4; j++)
            aob[(tr + i*8)*NC + tc + j*32] = f2bf(O[i][j] * linv[i]);
}

// ---------------- K4: proj + bias + residual (fp32 out) ----------------
// grid (128 n-tiles, 2 o-tiles, 4 b), block 256. tile 64o x 32n.
__global__ __launch_bounds__(256) void proj_kernel(const u16* __restrict__ ao,
                                                   const float* __restrict__ w,
                                                   const float* __restrict__ bias,
                                                   const float* __restrict__ x,
                                                   float* __restrict__ out){
    int n0 = blockIdx.x * 32;
    int o0 = blockIdx.y * 64;
    int b  = blockIdx.z;
    __shared__ float Wt[64][132];   // [o][c] pad 132
    __shared__ float At[32][132];   // [n][c] pad 132
    int t = threadIdx.x;

    const float4* w4 = (const float4*)(w + (size_t)o0 * NC);
    #pragma unroll
    for (int i = 0; i < 8; i++){
        int f = t + i*256;
        int o = f >> 5, c4 = f & 31;
        *(float4*)&Wt[o][c4*4] = w4[f];
    }
    const u16* aob = ao + ((size_t)b*HW + n0) * NC;
    #pragma unroll
    for (int i = 0; i < 2; i++){
        int f = t + i*256;
        int n = f >> 4, c8 = f & 15;
        uint4 u = *(const uint4*)(aob + (size_t)n*NC + c8*8);
        float v[8]; unpack8(u, v);
        *(float4*)&At[n][c8*8]   = make_float4(v[0],v[1],v[2],v[3]);
        *(float4*)&At[n][c8*8+4] = make_float4(v[4],v[5],v[6],v[7]);
    }
    __syncthreads();

    int to = t >> 4, tn = t & 15;   // o = o0+to+16i (4), n = n0+tn+16j (2)
    float acc[4][2] = {};
    for (int c = 0; c < 128; c++){
        float wv[4], xv[2];
        #pragma unroll
        for (int i = 0; i < 4; i++) wv[i] = Wt[to + i*16][c];
        #pragma unroll
        for (int j = 0; j < 2; j++) xv[j] = At[tn + j*16][c];
        #pragma unroll
        for (int i = 0; i < 4; i++)
            #pragma unroll
            for (int j = 0; j < 2; j++) acc[i][j] += wv[i]*xv[j];
    }
    #pragma unroll
    for (int i = 0; i < 4; i++){
        int o = o0 + to + i*16;
        float bo = bias[o];
        #pragma unroll
        for (int j = 0; j < 2; j++){
            size_t idx = ((size_t)b*NC + o)*HW + n0 + tn + j*16;
            out[idx] = x[idx] + bo + acc[i][j];
        }
    }
}

extern "C" void kernel_launch(void* const* d_in, const int* in_sizes, int n_in,
                              void* d_out, int out_size, void* d_ws, size_t ws_size,
                              hipStream_t stream){
    const float* x      = (const float*)d_in[0];
    const float* norm_w = (const float*)d_in[1];
    const float* norm_b = (const float*)d_in[2];
    const float* qkv_w  = (const float*)d_in[3];
    const float* qkv_b  = (const float*)d_in[4];
    const float* proj_w = (const float*)d_in[5];
    const float* proj_b = (const float*)d_in[6];
    float* out = (float*)d_out;

    // ws layout: stats(256B) | qkv bf16 (4*384*4096*2 = 12582912 B) | ao bf16 (4194304 B)
    float* stats = (float*)d_ws;
    u16* qkv = (u16*)((char*)d_ws + 256);
    u16* ao  = (u16*)((char*)d_ws + 256 + 12582912);

    gn_stats_kernel<<<32, 256, 0, stream>>>(x, stats);
    qkv_kernel<<<dim3(64, 6, 4), 256, 0, stream>>>(x, stats, norm_w, norm_b, qkv_w, qkv_b, qkv);
    attn_kernel<<<dim3(128, 4), 256, 0, stream>>>(qkv, ao);
    proj_kernel<<<dim3(128, 2, 4), 256, 0, stream>>>(ao, proj_w, proj_b, x, out);
}

// Round 3
// 259.709 us; speedup vs baseline: 3.7724x; 3.7724x over previous
//
#include <hip/hip_runtime.h>

typedef unsigned short u16;
typedef unsigned int   u32;

#define HW 4096
#define NC 128

typedef __bf16 bf16x8 __attribute__((ext_vector_type(8)));
typedef float  f32x16 __attribute__((ext_vector_type(16)));

__device__ __forceinline__ bf16x8 as_bf8(uint4 u){
    union { uint4 u; bf16x8 b; } c; c.u = u; return c.b;
}
__device__ __forceinline__ u16 f2bf(float f){
    u32 u = __float_as_uint(f);
    return (u16)((u + 0x7fffu + ((u >> 16) & 1u)) >> 16);
}
__device__ __forceinline__ u32 pack2(float a, float b){   // round-to-nearest (no tie fix)
    return ((__float_as_uint(a) + 0x8000u) >> 16) | ((__float_as_uint(b) + 0x8000u) & 0xffff0000u);
}
__device__ __forceinline__ float bf_lo(u32 u){ return __uint_as_float(u << 16); }
__device__ __forceinline__ float bf_hi(u32 u){ return __uint_as_float(u & 0xffff0000u); }
__device__ __forceinline__ void unpack8(uint4 u, float* v){
    v[0]=bf_lo(u.x); v[1]=bf_hi(u.x); v[2]=bf_lo(u.y); v[3]=bf_hi(u.y);
    v[4]=bf_lo(u.z); v[5]=bf_hi(u.z); v[6]=bf_lo(u.w); v[7]=bf_hi(u.w);
}

// ---------------- K1: GroupNorm stats. grid=32 (b*8+g), block=256 ----------------
__global__ __launch_bounds__(256) void gn_stats_kernel(const float* __restrict__ x,
                                                       float* __restrict__ stats){
    int bg = blockIdx.x;
    const float4* p = (const float4*)(x + (size_t)bg * 65536);
    float s = 0.f, ss = 0.f;
    for (int i = threadIdx.x; i < 16384; i += 256){
        float4 u = p[i];
        s  += u.x + u.y + u.z + u.w;
        ss += u.x*u.x + u.y*u.y + u.z*u.z + u.w*u.w;
    }
    #pragma unroll
    for (int off = 32; off > 0; off >>= 1){
        s  += __shfl_xor(s,  off);
        ss += __shfl_xor(ss, off);
    }
    __shared__ float rs[4], rss[4];
    int wid = threadIdx.x >> 6;
    if ((threadIdx.x & 63) == 0){ rs[wid] = s; rss[wid] = ss; }
    __syncthreads();
    if (threadIdx.x == 0){
        float S = rs[0]+rs[1]+rs[2]+rs[3];
        float SS = rss[0]+rss[1]+rss[2]+rss[3];
        float mean = S * (1.f/65536.f);
        float var  = SS * (1.f/65536.f) - mean*mean;
        stats[bg*2]   = mean;
        stats[bg*2+1] = rsqrtf(var + 1e-5f);
    }
}

// ---------------- K2: fused GN-apply + QKV GEMM ----------------
// grid (64 n-tiles, 6 o-tiles, 4 b), block 256. Q,K -> token-major [b][tok][128];
// V -> channel-major [b][c][4096]. All bf16.
__global__ __launch_bounds__(256) void qkv_kernel(const float* __restrict__ x,
                                                  const float* __restrict__ stats,
                                                  const float* __restrict__ gamma,
                                                  const float* __restrict__ beta,
                                                  const float* __restrict__ w,
                                                  const float* __restrict__ bias,
                                                  u16* __restrict__ Qws,
                                                  u16* __restrict__ Kws,
                                                  u16* __restrict__ Vws){
    int n0 = blockIdx.x * 64;
    int o0 = blockIdx.y * 64;
    int b  = blockIdx.z;
    __shared__ float Wt[64][128];   // [o][c] wave-uniform reads -> broadcast
    __shared__ float Xt[128][64];   // [c][n]
    int t = threadIdx.x;

    const float4* w4 = (const float4*)(w + (size_t)o0 * NC);
    #pragma unroll
    for (int i = 0; i < 8; i++){
        int f = t + i*256;
        int o = f >> 5, c4 = f & 31;
        *(float4*)&Wt[o][c4*4] = w4[f];
    }
    #pragma unroll
    for (int i = 0; i < 8; i++){
        int f = t + i*256;
        int c = f >> 4, m4 = f & 15;
        float4 u = *(const float4*)(x + ((size_t)b*NC + c)*HW + n0 + m4*4);
        float mean = stats[(b*8 + (c>>4))*2];
        float rstd = stats[(b*8 + (c>>4))*2 + 1];
        float ga = gamma[c] * rstd;
        float be = beta[c] - mean * ga;
        u.x = u.x*ga + be; u.y = u.y*ga + be; u.z = u.z*ga + be; u.w = u.w*ga + be;
        *(float4*)&Xt[c][m4*4] = u;
    }
    __syncthreads();

    int lane = t & 63, wid = t >> 6;   // wave owns 16 o-rows, lane = token
    float acc[16] = {};
    for (int c4 = 0; c4 < 32; c4++){
        float xv[4];
        #pragma unroll
        for (int k = 0; k < 4; k++) xv[k] = Xt[c4*4+k][lane];
        #pragma unroll
        for (int i = 0; i < 16; i++){
            float4 wv = *(float4*)&Wt[wid*16 + i][c4*4];
            acc[i] += wv.x*xv[0] + wv.y*xv[1] + wv.z*xv[2] + wv.w*xv[3];
        }
    }
    int y = blockIdx.y;
    if (y < 4){
        // Q or K: token-major, pack 16 consecutive channels -> 2 uint4 stores
        u16* dst = (y < 2) ? Qws : Kws;
        int o0r = (y < 2) ? o0 : (o0 - 128);
        u32 pk[8];
        #pragma unroll
        for (int j = 0; j < 8; j++){
            float a0 = acc[2*j]   + bias[o0 + wid*16 + 2*j];
            float a1 = acc[2*j+1] + bias[o0 + wid*16 + 2*j+1];
            pk[j] = (u32)f2bf(a0) | ((u32)f2bf(a1) << 16);
        }
        u16* d = dst + ((size_t)b*HW + n0 + lane)*NC + o0r + wid*16;
        *(uint4*)d       = make_uint4(pk[0],pk[1],pk[2],pk[3]);
        *(uint4*)(d + 8) = make_uint4(pk[4],pk[5],pk[6],pk[7]);
    } else {
        // V: channel-major
        #pragma unroll
        for (int i = 0; i < 16; i++){
            int o = o0 + wid*16 + i;
            Vws[((size_t)b*NC + (o - 256))*HW + n0 + lane] = f2bf(acc[i] + bias[o]);
        }
    }
}

// ---------------- K3: MFMA flash attention ----------------
// grid (64 q-tiles, 2 ksplit, 4 b), block 128 (2 waves x 32 qrows). TK=64.
// S' = K*Q^T via mfma_32x32x16_bf16; softmax w/ fixed offset (no running max);
// P round-trips LDS in A-fragment order; PV: A=P, B=V.
__global__ __launch_bounds__(128, 2) void attn_kernel(const u16* __restrict__ Qw,
                                                      const u16* __restrict__ Kw,
                                                      const u16* __restrict__ Vw,
                                                      u16* __restrict__ Opart,
                                                      float* __restrict__ lsum){
    int b = blockIdx.z, ksp = blockIdx.y, q0 = blockIdx.x * 64;
    int t = threadIdx.x, lane = t & 63, wv = t >> 6;
    __shared__ uint4 Kl[1024];      // frag (mb*8+ks)*64 + slot   (16 KB)
    __shared__ uint4 Vl[1024];      // frag (nb*4+ks)*64 + slot   (16 KB)
    __shared__ uint4 Pl[2][256];    // per-wave, frag ks*64+slot  (8 KB)
    const float SC = 0.08838834764831845f;   // 1/sqrt(128)

    // Q fragments (B-operand): qr = q0+wv*32+(lane&31), c = ks*16+(lane>>5)*8
    uint4 qf[8];
    const u16* qb = Qw + ((size_t)b*HW + q0 + wv*32 + (lane&31))*NC + ((lane>>5)<<3);
    #pragma unroll
    for (int ks = 0; ks < 8; ks++) qf[ks] = *(const uint4*)(qb + ks*16);

    f32x16 O0, O1, O2, O3;
    #pragma unroll
    for (int r = 0; r < 16; r++){ O0[r]=0.f; O1[r]=0.f; O2[r]=0.f; O3[r]=0.f; }
    float l_i = 0.f;

    const u16* kbase = Kw + ((size_t)b*HW + ksp*2048)*NC;
    const u16* vbase = Vw + (size_t)b*NC*HW + ksp*2048;

    for (int it = 0; it < 32; it++){
        __syncthreads();
        // stage K tile 64tok x 128c -> fragment order
        const uint4* kg = (const uint4*)(kbase + (size_t)it*64*NC);
        #pragma unroll
        for (int i = 0; i < 8; i++){
            int f = t + i*128;
            int tok = f >> 4, c8 = f & 15;
            Kl[(((tok>>5)*8 + (c8>>1))<<6) + (tok&31) + ((c8&1)<<5)] = kg[f];
        }
        // stage V tile 128c x 64tok -> fragment order
        #pragma unroll
        for (int i = 0; i < 8; i++){
            int f = t + i*128;
            int c = f >> 3, t8 = f & 7;
            uint4 u = *(const uint4*)(vbase + (size_t)c*HW + it*64 + t8*8);
            Vl[(((c>>5)*4 + (t8>>1))<<6) + (c&31) + ((t8&1)<<5)] = u;
        }
        __syncthreads();

        // S' = K·Q^T : D[kt][qr], 2 m-blocks x 8 k-steps
        f32x16 S0, S1;
        #pragma unroll
        for (int r = 0; r < 16; r++){ S0[r]=0.f; S1[r]=0.f; }
        #pragma unroll
        for (int ks = 0; ks < 8; ks++){
            bf16x8 qv = as_bf8(qf[ks]);
            S0 = __builtin_amdgcn_mfma_f32_32x32x16_bf16(as_bf8(Kl[(ks<<6) + lane]),      qv, S0, 0,0,0);
            S1 = __builtin_amdgcn_mfma_f32_32x32x16_bf16(as_bf8(Kl[((8+ks)<<6) + lane]),  qv, S1, 0,0,0);
        }

        // softmax (fixed offset -8, no running max), pack P to LDS A-frag order
        float psum = 0.f;
        #pragma unroll
        for (int q = 0; q < 4; q++){
            float e0 = __expf(__fmaf_rn(S0[q*4+0], SC, -8.f));
            float e1 = __expf(__fmaf_rn(S0[q*4+1], SC, -8.f));
            float e2 = __expf(__fmaf_rn(S0[q*4+2], SC, -8.f));
            float e3 = __expf(__fmaf_rn(S0[q*4+3], SC, -8.f));
            psum += (e0+e1)+(e2+e3);
            int slot = ((q>>1)<<6) + (lane&31) + ((q&1)<<5);
            *(uint2*)((char*)&Pl[wv][slot] + ((lane>>5)<<3)) = make_uint2(pack2(e0,e1), pack2(e2,e3));
        }
        #pragma unroll
        for (int q = 0; q < 4; q++){
            float e0 = __expf(__fmaf_rn(S1[q*4+0], SC, -8.f));
            float e1 = __expf(__fmaf_rn(S1[q*4+1], SC, -8.f));
            float e2 = __expf(__fmaf_rn(S1[q*4+2], SC, -8.f));
            float e3 = __expf(__fmaf_rn(S1[q*4+3], SC, -8.f));
            psum += (e0+e1)+(e2+e3);
            int slot = ((2 + (q>>1))<<6) + (lane&31) + ((q&1)<<5);
            *(uint2*)((char*)&Pl[wv][slot] + ((lane>>5)<<3)) = make_uint2(pack2(e0,e1), pack2(e2,e3));
        }
        psum += __shfl_xor(psum, 32);
        l_i += psum;

        // PV: O[qr][c] += P·V, 4 n-blocks x 4 k-steps
        #pragma unroll
        for (int ks = 0; ks < 4; ks++){
            bf16x8 pa = as_bf8(Pl[wv][(ks<<6) + lane]);
            O0 = __builtin_amdgcn_mfma_f32_32x32x16_bf16(pa, as_bf8(Vl[((0*4+ks)<<6) + lane]), O0, 0,0,0);
            O1 = __builtin_amdgcn_mfma_f32_32x32x16_bf16(pa, as_bf8(Vl[((1*4+ks)<<6) + lane]), O1, 0,0,0);
            O2 = __builtin_amdgcn_mfma_f32_32x32x16_bf16(pa, as_bf8(Vl[((2*4+ks)<<6) + lane]), O2, 0,0,0);
            O3 = __builtin_amdgcn_mfma_f32_32x32x16_bf16(pa, as_bf8(Vl[((3*4+ks)<<6) + lane]), O3, 0,0,0);
        }
    }

    if (lane < 32) lsum[((size_t)(ksp*4 + b))*HW + q0 + wv*32 + lane] = l_i;

    u16* ob = Opart + (((size_t)(ksp*4 + b))*HW + q0 + wv*32)*NC;
    #pragma unroll
    for (int r = 0; r < 16; r++){
        int qr = (r&3) + 8*(r>>2) + 4*(lane>>5);
        int c  = lane & 31;
        ob[qr*NC +      c] = f2bf(O0[r]);
        ob[qr*NC + 32 + c] = f2bf(O1[r]);
        ob[qr*NC + 64 + c] = f2bf(O2[r]);
        ob[qr*NC + 96 + c] = f2bf(O3[r]);
    }
}

// ---------------- K3b: combine the 2 K-split partials ----------------
// grid 1024, block 256. out = (O_0 + O_1) / (l_0 + l_1), token-major bf16.
__global__ __launch_bounds__(256) void combine_kernel(const u16* __restrict__ Op,
                                                      const float* __restrict__ lsum,
                                                      u16* __restrict__ ao){
    int idx = blockIdx.x*256 + threadIdx.x;
    int row = idx >> 4, cg = idx & 15;
    float inv = 1.f / (lsum[row] + lsum[16384 + row]);
    uint4 u0 = *(const uint4*)(Op + (size_t)row*NC + cg*8);
    uint4 u1 = *(const uint4*)(Op + (size_t)2097152 + (size_t)row*NC + cg*8);
    float v0[8], v1[8];
    unpack8(u0, v0); unpack8(u1, v1);
    u32 pk[4];
    #pragma unroll
    for (int j = 0; j < 4; j++){
        float r0 = (v0[2*j]   + v1[2*j])   * inv;
        float r1 = (v0[2*j+1] + v1[2*j+1]) * inv;
        pk[j] = (u32)f2bf(r0) | ((u32)f2bf(r1) << 16);
    }
    *(uint4*)(ao + (size_t)row*NC + cg*8) = make_uint4(pk[0],pk[1],pk[2],pk[3]);
}

// ---------------- K4: proj + bias + residual (fp32 out) ----------------
// grid (128 n-tiles, 2 o-tiles, 4 b), block 256. tile 64o x 32n.
__global__ __launch_bounds__(256) void proj_kernel(const u16* __restrict__ ao,
                                                   const float* __restrict__ w,
                                                   const float* __restrict__ bias,
                                                   const float* __restrict__ x,
                                                   float* __restrict__ out){
    int n0 = blockIdx.x * 32;
    int o0 = blockIdx.y * 64;
    int b  = blockIdx.z;
    __shared__ float Wt[64][132];
    __shared__ float At[32][132];
    int t = threadIdx.x;

    const float4* w4 = (const float4*)(w + (size_t)o0 * NC);
    #pragma unroll
    for (int i = 0; i < 8; i++){
        int f = t + i*256;
        int o = f >> 5, c4 = f & 31;
        *(float4*)&Wt[o][c4*4] = w4[f];
    }
    const u16* aob = ao + ((size_t)b*HW + n0) * NC;
    #pragma unroll
    for (int i = 0; i < 2; i++){
        int f = t + i*256;
        int n = f >> 4, c8 = f & 15;
        uint4 u = *(const uint4*)(aob + (size_t)n*NC + c8*8);
        float v[8]; unpack8(u, v);
        *(float4*)&At[n][c8*8]   = make_float4(v[0],v[1],v[2],v[3]);
        *(float4*)&At[n][c8*8+4] = make_float4(v[4],v[5],v[6],v[7]);
    }
    __syncthreads();

    int to = t >> 4, tn = t & 15;
    float acc[4][2] = {};
    for (int c = 0; c < 128; c++){
        float wvv[4], xv[2];
        #pragma unroll
        for (int i = 0; i < 4; i++) wvv[i] = Wt[to + i*16][c];
        #pragma unroll
        for (int j = 0; j < 2; j++) xv[j] = At[tn + j*16][c];
        #pragma unroll
        for (int i = 0; i < 4; i++)
            #pragma unroll
            for (int j = 0; j < 2; j++) acc[i][j] += wvv[i]*xv[j];
    }
    #pragma unroll
    for (int i = 0; i < 4; i++){
        int o = o0 + to + i*16;
        float bo = bias[o];
        #pragma unroll
        for (int j = 0; j < 2; j++){
            size_t idx = ((size_t)b*NC + o)*HW + n0 + tn + j*16;
            out[idx] = x[idx] + bo + acc[i][j];
        }
    }
}

extern "C" void kernel_launch(void* const* d_in, const int* in_sizes, int n_in,
                              void* d_out, int out_size, void* d_ws, size_t ws_size,
                              hipStream_t stream){
    const float* x      = (const float*)d_in[0];
    const float* norm_w = (const float*)d_in[1];
    const float* norm_b = (const float*)d_in[2];
    const float* qkv_w  = (const float*)d_in[3];
    const float* qkv_b  = (const float*)d_in[4];
    const float* proj_w = (const float*)d_in[5];
    const float* proj_b = (const float*)d_in[6];
    float* out = (float*)d_out;

    // ws: stats 256B | Qws 4.19MB | Kws 4.19MB | Vws 4.19MB | lsum 128KB  (~12.7MB)
    float* stats = (float*)d_ws;
    u16* Qws = (u16*)((char*)d_ws + 256);
    u16* Kws = (u16*)((char*)d_ws + 256 + 4194304);
    u16* Vws = (u16*)((char*)d_ws + 256 + 8388608);
    float* lsum = (float*)((char*)d_ws + 256 + 12582912);
    // O partials (2 splits x 4b x 4096 x 128 bf16 = 8.39MB) live in d_out as scratch,
    // fully overwritten by proj_kernel afterwards.
    u16* Opart = (u16*)d_out;
    u16* ao = Qws;   // Q retired after attn; combiner reuses its space

    gn_stats_kernel<<<32, 256, 0, stream>>>(x, stats);
    qkv_kernel<<<dim3(64, 6, 4), 256, 0, stream>>>(x, stats, norm_w, norm_b, qkv_w, qkv_b, Qws, Kws, Vws);
    attn_kernel<<<dim3(64, 2, 4), 128, 0, stream>>>(Qws, Kws, Vws, Opart, lsum);
    combine_kernel<<<1024, 256, 0, stream>>>(Opart, lsum, ao);
    proj_kernel<<<dim3(128, 2, 4), 256, 0, stream>>>(ao, proj_w, proj_b, x, out);
}

// Round 4
// 253.496 us; speedup vs baseline: 3.8649x; 1.0245x over previous
//
#include <hip/hip_runtime.h>

typedef unsigned short u16;
typedef unsigned int   u32;

#define HW 4096
#define NC 128

typedef __bf16 bf16x8 __attribute__((ext_vector_type(8)));
typedef float  f32x16 __attribute__((ext_vector_type(16)));

__device__ __forceinline__ bf16x8 as_bf8(uint4 u){
    union { uint4 u; bf16x8 b; } c; c.u = u; return c.b;
}
__device__ __forceinline__ u16 f2bf(float f){
    u32 u = __float_as_uint(f);
    return (u16)((u + 0x7fffu + ((u >> 16) & 1u)) >> 16);
}
__device__ __forceinline__ u32 pack2(float a, float b){
    return ((__float_as_uint(a) + 0x8000u) >> 16) | ((__float_as_uint(b) + 0x8000u) & 0xffff0000u);
}

// ---------------- K0: zero O-accumulator (in d_out) and l-accumulator ----------------
// grid 2064 x 256: 524288 float4 for Oacc + 4096 float4 for lacc.
__global__ __launch_bounds__(256) void zero_kernel(float4* __restrict__ o,
                                                   float4* __restrict__ l){
    int i = blockIdx.x*256 + threadIdx.x;
    float4 z = make_float4(0.f,0.f,0.f,0.f);
    if (i < 524288) o[i] = z;
    else            l[i - 524288] = z;
}

// ---------------- K1: GroupNorm stats. grid=32 (b*8+g), block=256 ----------------
__global__ __launch_bounds__(256) void gn_stats_kernel(const float* __restrict__ x,
                                                       float* __restrict__ stats){
    int bg = blockIdx.x;
    const float4* p = (const float4*)(x + (size_t)bg * 65536);
    float s = 0.f, ss = 0.f;
    for (int i = threadIdx.x; i < 16384; i += 256){
        float4 u = p[i];
        s  += u.x + u.y + u.z + u.w;
        ss += u.x*u.x + u.y*u.y + u.z*u.z + u.w*u.w;
    }
    #pragma unroll
    for (int off = 32; off > 0; off >>= 1){
        s  += __shfl_xor(s,  off);
        ss += __shfl_xor(ss, off);
    }
    __shared__ float rs[4], rss[4];
    int wid = threadIdx.x >> 6;
    if ((threadIdx.x & 63) == 0){ rs[wid] = s; rss[wid] = ss; }
    __syncthreads();
    if (threadIdx.x == 0){
        float S = rs[0]+rs[1]+rs[2]+rs[3];
        float SS = rss[0]+rss[1]+rss[2]+rss[3];
        float mean = S * (1.f/65536.f);
        float var  = SS * (1.f/65536.f) - mean*mean;
        stats[bg*2]   = mean;
        stats[bg*2+1] = rsqrtf(var + 1e-5f);
    }
}

// ---------------- K2: fused GN-apply + QKV GEMM, outputs in MFMA-fragment order ----------------
// Q/K: [b][blk32][ks(8)][slot(64)] x 8ch-uint4 : slot l = channels ks*16+(l>>5)*8.. of row blk*32+(l&31)
// V  : [b][it(64)][nb(4)][ks(4)][slot(64)] x 8tok : slot l = tokens it*64+ks*16+(l>>5)*8.. of ch nb*32+(l&31)
__global__ __launch_bounds__(256) void qkv_kernel(const float* __restrict__ x,
                                                  const float* __restrict__ stats,
                                                  const float* __restrict__ gamma,
                                                  const float* __restrict__ beta,
                                                  const float* __restrict__ w,
                                                  const float* __restrict__ bias,
                                                  u16* __restrict__ Qf,
                                                  u16* __restrict__ Kf,
                                                  u16* __restrict__ Vf){
    int n0 = blockIdx.x * 64;
    int o0 = blockIdx.y * 64;
    int b  = blockIdx.z;
    __shared__ float Wt[64][128];
    __shared__ float Xt[128][64];
    int t = threadIdx.x;

    const float4* w4 = (const float4*)(w + (size_t)o0 * NC);
    #pragma unroll
    for (int i = 0; i < 8; i++){
        int f = t + i*256;
        int o = f >> 5, c4 = f & 31;
        *(float4*)&Wt[o][c4*4] = w4[f];
    }
    #pragma unroll
    for (int i = 0; i < 8; i++){
        int f = t + i*256;
        int c = f >> 4, m4 = f & 15;
        float4 u = *(const float4*)(x + ((size_t)b*NC + c)*HW + n0 + m4*4);
        float mean = stats[(b*8 + (c>>4))*2];
        float rstd = stats[(b*8 + (c>>4))*2 + 1];
        float ga = gamma[c] * rstd;
        float be = beta[c] - mean * ga;
        u.x = u.x*ga + be; u.y = u.y*ga + be; u.z = u.z*ga + be; u.w = u.w*ga + be;
        *(float4*)&Xt[c][m4*4] = u;
    }
    __syncthreads();

    int lane = t & 63, wid = t >> 6;   // wave owns 16 o-rows, lane = token
    float acc[16] = {};
    for (int c4 = 0; c4 < 32; c4++){
        float xv[4];
        #pragma unroll
        for (int k = 0; k < 4; k++) xv[k] = Xt[c4*4+k][lane];
        #pragma unroll
        for (int i = 0; i < 16; i++){
            float4 wv = *(float4*)&Wt[wid*16 + i][c4*4];
            acc[i] += wv.x*xv[0] + wv.y*xv[1] + wv.z*xv[2] + wv.w*xv[3];
        }
    }
    int y = blockIdx.y;
    if (y < 4){
        u16* dst = (y < 2) ? Qf : Kf;
        int o0r = (y < 2) ? o0 : (o0 - 128);
        int ks = (o0r >> 4) + wid;           // thread's 16 channels = one ks
        u32 pk[8];
        #pragma unroll
        for (int j = 0; j < 8; j++){
            float a0 = acc[2*j]   + bias[o0 + wid*16 + 2*j];
            float a1 = acc[2*j+1] + bias[o0 + wid*16 + 2*j+1];
            pk[j] = (u32)f2bf(a0) | ((u32)f2bf(a1) << 16);
        }
        size_t fi = (((size_t)b*128 + (n0>>5) + (lane>>5))*8 + ks)*64 + (lane&31);
        uint4* d4 = (uint4*)dst + fi;
        d4[0]  = make_uint4(pk[0],pk[1],pk[2],pk[3]);   // channel half 0 (slot l)
        d4[32] = make_uint4(pk[4],pk[5],pk[6],pk[7]);   // channel half 1 (slot l+32)
    } else {
        int c0 = o0 - 256 + wid*16;
        int tok = n0 + lane;
        int nb = c0 >> 5, cl = c0 & 31;
        size_t base = ((((size_t)b*64 + (tok>>6))*4 + nb)*4 + ((tok>>4)&3))*64
                      + (((tok>>3)&1)<<5) + cl;
        u16* d = Vf + base*8 + (tok&7);
        #pragma unroll
        for (int i = 0; i < 16; i++)
            d[i*8] = f2bf(acc[i] + bias[o0 + wid*16 + i]);
    }
}

// ---------------- K3: MFMA flash attention ----------------
// grid (32 q-blocks of 128 rows, 4 ksplit, 4 b), block 256 = 4 waves x 32 qrows. TK=64, 16 iters.
// Staging is a straight fragment-order copy; O/l accumulated into global via atomics.
__global__ __launch_bounds__(256, 2) void attn_kernel(const uint4* __restrict__ Qf,
                                                      const uint4* __restrict__ Kf,
                                                      const uint4* __restrict__ Vf,
                                                      float* __restrict__ Oacc,
                                                      float* __restrict__ lacc){
    int b = blockIdx.z, ksp = blockIdx.y;
    int t = threadIdx.x, lane = t & 63, wv = t >> 6;
    int qb = blockIdx.x*4 + wv;              // 32-row q-block owned by this wave
    __shared__ uint4 Kl[1024];               // frag (mbL*8+ks)*64 + slot
    __shared__ uint4 Vl[1024];               // frag (nb*4+ks)*64 + slot
    __shared__ uint4 Pl[4][256];             // per-wave A-frag of P
    const float SC = 0.08838834764831845f;   // 1/sqrt(128)

    uint4 qf[8];
    const uint4* qptr = Qf + (((size_t)b*128 + qb)*8)*64 + lane;
    #pragma unroll
    for (int ks = 0; ks < 8; ks++) qf[ks] = qptr[ks*64];

    f32x16 O0, O1, O2, O3;
    #pragma unroll
    for (int r = 0; r < 16; r++){ O0[r]=0.f; O1[r]=0.f; O2[r]=0.f; O3[r]=0.f; }
    float l_i = 0.f;

    const uint4* kg = Kf + ((size_t)b*128 + ksp*32)*512;   // 1024 uint4 per iter
    const uint4* vg = Vf + ((size_t)b*64  + ksp*16)*1024;

    uint4 kr[4], vr[4];
    #pragma unroll
    for (int i = 0; i < 4; i++){ kr[i] = kg[t + i*256]; vr[i] = vg[t + i*256]; }

    for (int it = 0; it < 16; it++){
        __syncthreads();                      // prev tile's reads done
        #pragma unroll
        for (int i = 0; i < 4; i++){ Kl[t + i*256] = kr[i]; Vl[t + i*256] = vr[i]; }
        __syncthreads();                      // tile visible
        if (it < 15){
            const uint4* kg2 = kg + (it+1)*1024;
            const uint4* vg2 = vg + (it+1)*1024;
            #pragma unroll
            for (int i = 0; i < 4; i++){ kr[i] = kg2[t + i*256]; vr[i] = vg2[t + i*256]; }
        }

        // S' = K·Q^T : D[kt][qr]
        f32x16 S0, S1;
        #pragma unroll
        for (int r = 0; r < 16; r++){ S0[r]=0.f; S1[r]=0.f; }
        #pragma unroll
        for (int ks = 0; ks < 8; ks++){
            bf16x8 qv = as_bf8(qf[ks]);
            S0 = __builtin_amdgcn_mfma_f32_32x32x16_bf16(as_bf8(Kl[(ks<<6) + lane]),     qv, S0, 0,0,0);
            S1 = __builtin_amdgcn_mfma_f32_32x32x16_bf16(as_bf8(Kl[((8+ks)<<6) + lane]), qv, S1, 0,0,0);
        }

        // softmax (fixed offset, no running max); P -> per-wave LDS in A-frag order
        float psum = 0.f;
        #pragma unroll
        for (int q = 0; q < 4; q++){
            float e0 = __expf(__fmaf_rn(S0[q*4+0], SC, -8.f));
            float e1 = __expf(__fmaf_rn(S0[q*4+1], SC, -8.f));
            float e2 = __expf(__fmaf_rn(S0[q*4+2], SC, -8.f));
            float e3 = __expf(__fmaf_rn(S0[q*4+3], SC, -8.f));
            psum += (e0+e1)+(e2+e3);
            int slot = ((q>>1)<<6) + (lane&31) + ((q&1)<<5);
            *(uint2*)((char*)&Pl[wv][slot] + ((lane>>5)<<3)) = make_uint2(pack2(e0,e1), pack2(e2,e3));
        }
        #pragma unroll
        for (int q = 0; q < 4; q++){
            float e0 = __expf(__fmaf_rn(S1[q*4+0], SC, -8.f));
            float e1 = __expf(__fmaf_rn(S1[q*4+1], SC, -8.f));
            float e2 = __expf(__fmaf_rn(S1[q*4+2], SC, -8.f));
            float e3 = __expf(__fmaf_rn(S1[q*4+3], SC, -8.f));
            psum += (e0+e1)+(e2+e3);
            int slot = ((2 + (q>>1))<<6) + (lane&31) + ((q&1)<<5);
            *(uint2*)((char*)&Pl[wv][slot] + ((lane>>5)<<3)) = make_uint2(pack2(e0,e1), pack2(e2,e3));
        }
        psum += __shfl_xor(psum, 32);
        l_i += psum;

        // PV: O[qr][c] += P·V
        #pragma unroll
        for (int ks = 0; ks < 4; ks++){
            bf16x8 pa = as_bf8(Pl[wv][(ks<<6) + lane]);
            O0 = __builtin_amdgcn_mfma_f32_32x32x16_bf16(pa, as_bf8(Vl[((0*4+ks)<<6) + lane]), O0, 0,0,0);
            O1 = __builtin_amdgcn_mfma_f32_32x32x16_bf16(pa, as_bf8(Vl[((1*4+ks)<<6) + lane]), O1, 0,0,0);
            O2 = __builtin_amdgcn_mfma_f32_32x32x16_bf16(pa, as_bf8(Vl[((2*4+ks)<<6) + lane]), O2, 0,0,0);
            O3 = __builtin_amdgcn_mfma_f32_32x32x16_bf16(pa, as_bf8(Vl[((3*4+ks)<<6) + lane]), O3, 0,0,0);
        }
    }

    if (lane < 32) atomicAdd(&lacc[(size_t)b*HW + qb*32 + lane], l_i);
    float* ob = Oacc + ((size_t)b*HW + qb*32)*NC;
    #pragma unroll
    for (int r = 0; r < 16; r++){
        int qr = (r&3) + 8*(r>>2) + 4*(lane>>5);
        int c  = lane & 31;
        atomicAdd(&ob[qr*NC +      c], O0[r]);
        atomicAdd(&ob[qr*NC + 32 + c], O1[r]);
        atomicAdd(&ob[qr*NC + 64 + c], O2[r]);
        atomicAdd(&ob[qr*NC + 96 + c], O3[r]);
    }
}

// ---------------- K3b: normalize O by l, write bf16 token-major ao ----------------
// grid 1024 x 256: thread = 8 channels of one token.
__global__ __launch_bounds__(256) void normalize_kernel(const float* __restrict__ Oacc,
                                                        const float* __restrict__ lacc,
                                                        u16* __restrict__ ao){
    int idx = blockIdx.x*256 + threadIdx.x;
    int row = idx >> 4, cg = idx & 15;
    float inv = 1.f / lacc[row];
    float4 a = *(const float4*)(Oacc + (size_t)row*NC + cg*8);
    float4 c = *(const float4*)(Oacc + (size_t)row*NC + cg*8 + 4);
    uint4 o;
    o.x = (u32)f2bf(a.x*inv) | ((u32)f2bf(a.y*inv) << 16);
    o.y = (u32)f2bf(a.z*inv) | ((u32)f2bf(a.w*inv) << 16);
    o.z = (u32)f2bf(c.x*inv) | ((u32)f2bf(c.y*inv) << 16);
    o.w = (u32)f2bf(c.z*inv) | ((u32)f2bf(c.w*inv) << 16);
    *(uint4*)(ao + (size_t)row*NC + cg*8) = o;
}

// ---------------- K4: proj + bias + residual (fp32 out) ----------------
__global__ __launch_bounds__(256) void proj_kernel(const u16* __restrict__ ao,
                                                   const float* __restrict__ w,
                                                   const float* __restrict__ bias,
                                                   const float* __restrict__ x,
                                                   float* __restrict__ out){
    int n0 = blockIdx.x * 32;
    int o0 = blockIdx.y * 64;
    int b  = blockIdx.z;
    __shared__ float Wt[64][132];
    __shared__ float At[32][132];
    int t = threadIdx.x;

    const float4* w4 = (const float4*)(w + (size_t)o0 * NC);
    #pragma unroll
    for (int i = 0; i < 8; i++){
        int f = t + i*256;
        int o = f >> 5, c4 = f & 31;
        *(float4*)&Wt[o][c4*4] = w4[f];
    }
    const u16* aob = ao + ((size_t)b*HW + n0) * NC;
    #pragma unroll
    for (int i = 0; i < 2; i++){
        int f = t + i*256;
        int n = f >> 4, c8 = f & 15;
        uint4 u = *(const uint4*)(aob + (size_t)n*NC + c8*8);
        At[n][c8*8+0] = __uint_as_float(u.x << 16);
        At[n][c8*8+1] = __uint_as_float(u.x & 0xffff0000u);
        At[n][c8*8+2] = __uint_as_float(u.y << 16);
        At[n][c8*8+3] = __uint_as_float(u.y & 0xffff0000u);
        At[n][c8*8+4] = __uint_as_float(u.z << 16);
        At[n][c8*8+5] = __uint_as_float(u.z & 0xffff0000u);
        At[n][c8*8+6] = __uint_as_float(u.w << 16);
        At[n][c8*8+7] = __uint_as_float(u.w & 0xffff0000u);
    }
    __syncthreads();

    int to = t >> 4, tn = t & 15;
    float acc[4][2] = {};
    for (int c = 0; c < 128; c++){
        float wvv[4], xv[2];
        #pragma unroll
        for (int i = 0; i < 4; i++) wvv[i] = Wt[to + i*16][c];
        #pragma unroll
        for (int j = 0; j < 2; j++) xv[j] = At[tn + j*16][c];
        #pragma unroll
        for (int i = 0; i < 4; i++)
            #pragma unroll
            for (int j = 0; j < 2; j++) acc[i][j] += wvv[i]*xv[j];
    }
    #pragma unroll
    for (int i = 0; i < 4; i++){
        int o = o0 + to + i*16;
        float bo = bias[o];
        #pragma unroll
        for (int j = 0; j < 2; j++){
            size_t idx = ((size_t)b*NC + o)*HW + n0 + tn + j*16;
            out[idx] = x[idx] + bo + acc[i][j];
        }
    }
}

extern "C" void kernel_launch(void* const* d_in, const int* in_sizes, int n_in,
                              void* d_out, int out_size, void* d_ws, size_t ws_size,
                              hipStream_t stream){
    const float* x      = (const float*)d_in[0];
    const float* norm_w = (const float*)d_in[1];
    const float* norm_b = (const float*)d_in[2];
    const float* qkv_w  = (const float*)d_in[3];
    const float* qkv_b  = (const float*)d_in[4];
    const float* proj_w = (const float*)d_in[5];
    const float* proj_b = (const float*)d_in[6];
    float* out = (float*)d_out;

    // ws: stats 256B | Qf 4.19MB | Kf 4.19MB | Vf 4.19MB | lacc 64KB   (~12.65MB)
    float* stats = (float*)d_ws;
    u16* Qf = (u16*)((char*)d_ws + 256);
    u16* Kf = (u16*)((char*)d_ws + 256 + 4194304);
    u16* Vf = (u16*)((char*)d_ws + 256 + 8388608);
    float* lacc = (float*)((char*)d_ws + 256 + 12582912);
    u16* ao = Qf;                 // Q retired after attn; normalize reuses its space
    float* Oacc = (float*)d_out;  // fp32 O accumulator lives in d_out until proj

    zero_kernel<<<2064, 256, 0, stream>>>((float4*)Oacc, (float4*)lacc);
    gn_stats_kernel<<<32, 256, 0, stream>>>(x, stats);
    qkv_kernel<<<dim3(64, 6, 4), 256, 0, stream>>>(x, stats, norm_w, norm_b, qkv_w, qkv_b, Qf, Kf, Vf);
    attn_kernel<<<dim3(32, 4, 4), 256, 0, stream>>>((const uint4*)Qf, (const uint4*)Kf, (const uint4*)Vf, Oacc, lacc);
    normalize_kernel<<<1024, 256, 0, stream>>>(Oacc, lacc, ao);
    proj_kernel<<<dim3(128, 2, 4), 256, 0, stream>>>(ao, proj_w, proj_b, x, out);
}

// Round 5
// 227.378 us; speedup vs baseline: 4.3088x; 1.1149x over previous
//
#include <hip/hip_runtime.h>

typedef unsigned short u16;
typedef unsigned int   u32;

#define HW 4096
#define NC 128

typedef __bf16 bf16x8 __attribute__((ext_vector_type(8)));
typedef float  f32x16 __attribute__((ext_vector_type(16)));

__device__ __forceinline__ bf16x8 as_bf8(uint4 u){
    union { uint4 u; bf16x8 b; } c; c.u = u; return c.b;
}
__device__ __forceinline__ u16 f2bf(float f){
    u32 u = __float_as_uint(f);
    return (u16)((u + 0x7fffu + ((u >> 16) & 1u)) >> 16);
}
__device__ __forceinline__ u32 pack2(float a, float b){
    return ((__float_as_uint(a) + 0x8000u) >> 16) | ((__float_as_uint(b) + 0x8000u) & 0xffff0000u);
}
__device__ __forceinline__ float bf_lo(u32 u){ return __uint_as_float(u << 16); }
__device__ __forceinline__ float bf_hi(u32 u){ return __uint_as_float(u & 0xffff0000u); }
__device__ __forceinline__ void unpack8(uint4 u, float* v){
    v[0]=bf_lo(u.x); v[1]=bf_hi(u.x); v[2]=bf_lo(u.y); v[3]=bf_hi(u.y);
    v[4]=bf_lo(u.z); v[5]=bf_hi(u.z); v[6]=bf_lo(u.w); v[7]=bf_hi(u.w);
}

// async global -> LDS, 16B per lane
#define GLOAD_LDS16(g, l) \
    __builtin_amdgcn_global_load_lds((const __attribute__((address_space(1))) u32*)(const void*)(g), \
                                     (__attribute__((address_space(3))) u32*)(void*)(l), 16, 0, 0)

// ---------------- K1: GroupNorm stats. grid=32 (b*8+g), block=256 ----------------
__global__ __launch_bounds__(256) void gn_stats_kernel(const float* __restrict__ x,
                                                       float* __restrict__ stats){
    int bg = blockIdx.x;
    const float4* p = (const float4*)(x + (size_t)bg * 65536);
    float s = 0.f, ss = 0.f;
    for (int i = threadIdx.x; i < 16384; i += 256){
        float4 u = p[i];
        s  += u.x + u.y + u.z + u.w;
        ss += u.x*u.x + u.y*u.y + u.z*u.z + u.w*u.w;
    }
    #pragma unroll
    for (int off = 32; off > 0; off >>= 1){
        s  += __shfl_xor(s,  off);
        ss += __shfl_xor(ss, off);
    }
    __shared__ float rs[4], rss[4];
    int wid = threadIdx.x >> 6;
    if ((threadIdx.x & 63) == 0){ rs[wid] = s; rss[wid] = ss; }
    __syncthreads();
    if (threadIdx.x == 0){
        float S = rs[0]+rs[1]+rs[2]+rs[3];
        float SS = rss[0]+rss[1]+rss[2]+rss[3];
        float mean = S * (1.f/65536.f);
        float var  = SS * (1.f/65536.f) - mean*mean;
        stats[bg*2]   = mean;
        stats[bg*2+1] = rsqrtf(var + 1e-5f);
    }
}

// ---------------- K2: fused GN-apply + QKV GEMM, outputs in MFMA-fragment order ----------------
// Q/K: [b][blk32][ks(8)][slot(64)] x 8ch-uint4 : slot l = channels ks*16+(l>>5)*8.. of row blk*32+(l&31)
// V  : [b][it(64)][nb(4)][ks(4)][slot(64)] x 8tok : slot l = tokens it*64+ks*16+(l>>5)*8.. of ch nb*32+(l&31)
__global__ __launch_bounds__(256) void qkv_kernel(const float* __restrict__ x,
                                                  const float* __restrict__ stats,
                                                  const float* __restrict__ gamma,
                                                  const float* __restrict__ beta,
                                                  const float* __restrict__ w,
                                                  const float* __restrict__ bias,
                                                  u16* __restrict__ Qf,
                                                  u16* __restrict__ Kf,
                                                  u16* __restrict__ Vf){
    int n0 = blockIdx.x * 64;
    int o0 = blockIdx.y * 64;
    int b  = blockIdx.z;
    __shared__ float Wt[64][128];
    __shared__ float Xt[128][64];
    int t = threadIdx.x;

    const float4* w4 = (const float4*)(w + (size_t)o0 * NC);
    #pragma unroll
    for (int i = 0; i < 8; i++){
        int f = t + i*256;
        int o = f >> 5, c4 = f & 31;
        *(float4*)&Wt[o][c4*4] = w4[f];
    }
    #pragma unroll
    for (int i = 0; i < 8; i++){
        int f = t + i*256;
        int c = f >> 4, m4 = f & 15;
        float4 u = *(const float4*)(x + ((size_t)b*NC + c)*HW + n0 + m4*4);
        float mean = stats[(b*8 + (c>>4))*2];
        float rstd = stats[(b*8 + (c>>4))*2 + 1];
        float ga = gamma[c] * rstd;
        float be = beta[c] - mean * ga;
        u.x = u.x*ga + be; u.y = u.y*ga + be; u.z = u.z*ga + be; u.w = u.w*ga + be;
        *(float4*)&Xt[c][m4*4] = u;
    }
    __syncthreads();

    int lane = t & 63, wid = t >> 6;   // wave owns 16 o-rows, lane = token
    float acc[16] = {};
    for (int c4 = 0; c4 < 32; c4++){
        float xv[4];
        #pragma unroll
        for (int k = 0; k < 4; k++) xv[k] = Xt[c4*4+k][lane];
        #pragma unroll
        for (int i = 0; i < 16; i++){
            float4 wv = *(float4*)&Wt[wid*16 + i][c4*4];
            acc[i] += wv.x*xv[0] + wv.y*xv[1] + wv.z*xv[2] + wv.w*xv[3];
        }
    }
    int y = blockIdx.y;
    if (y < 4){
        u16* dst = (y < 2) ? Qf : Kf;
        int o0r = (y < 2) ? o0 : (o0 - 128);
        int ks = (o0r >> 4) + wid;           // thread's 16 channels = one ks
        u32 pk[8];
        #pragma unroll
        for (int j = 0; j < 8; j++){
            float a0 = acc[2*j]   + bias[o0 + wid*16 + 2*j];
            float a1 = acc[2*j+1] + bias[o0 + wid*16 + 2*j+1];
            pk[j] = (u32)f2bf(a0) | ((u32)f2bf(a1) << 16);
        }
        size_t fi = (((size_t)b*128 + (n0>>5) + (lane>>5))*8 + ks)*64 + (lane&31);
        uint4* d4 = (uint4*)dst + fi;
        d4[0]  = make_uint4(pk[0],pk[1],pk[2],pk[3]);   // channel half 0
        d4[32] = make_uint4(pk[4],pk[5],pk[6],pk[7]);   // channel half 1
    } else {
        int c0 = o0 - 256 + wid*16;
        int tok = n0 + lane;
        int nb = c0 >> 5, cl = c0 & 31;
        size_t base = ((((size_t)b*64 + (tok>>6))*4 + nb)*4 + ((tok>>4)&3))*64
                      + (((tok>>3)&1)<<5) + cl;
        u16* d = Vf + base*8 + (tok&7);
        #pragma unroll
        for (int i = 0; i < 16; i++)
            d[i*8] = f2bf(acc[i] + bias[o0 + wid*16 + i]);
    }
}

// ---------------- K3: MFMA flash attention ----------------
// grid (64 q-blocks, 2 ksplit, 4 b), block 128 = 2 waves x 32 qrows. TK=64, 32 iters.
// K: async DMA -> LDS, double-buffered, 1 barrier/iter. V: direct fragment loads from L2.
// Partials: plain bf16 stores (no atomics) into d_out; l -> ws.
__global__ __launch_bounds__(128) void attn_kernel(const uint4* __restrict__ Qf,
                                                   const uint4* __restrict__ Kf,
                                                   const uint4* __restrict__ Vf,
                                                   u16* __restrict__ Opart,
                                                   float* __restrict__ lsum){
    int b = blockIdx.z, ksp = blockIdx.y;
    int t = threadIdx.x, lane = t & 63, wv = t >> 6;
    int qb = blockIdx.x*2 + wv;              // 32-row q-block of this wave (0..127)
    __shared__ uint4 Kl[2][1024];            // double-buffered K tile, frag order
    __shared__ uint4 Pl[2][256];             // per-wave A-frag of P
    const float SC = 0.08838834764831845f;   // 1/sqrt(128)

    uint4 qf[8];
    const uint4* qptr = Qf + ((size_t)b*128 + qb)*512 + lane;
    #pragma unroll
    for (int ks = 0; ks < 8; ks++) qf[ks] = qptr[ks*64];

    f32x16 O0, O1, O2, O3;
    #pragma unroll
    for (int r = 0; r < 16; r++){ O0[r]=0.f; O1[r]=0.f; O2[r]=0.f; O3[r]=0.f; }
    float l_i = 0.f;

    const uint4* kg = Kf + ((size_t)b*128 + ksp*64)*512;    // 1024 uint4 per iter
    const uint4* vg = Vf + ((size_t)b*64  + ksp*32)*1024;

    // prologue: DMA iter-0 K tile into buffer 0
    #pragma unroll
    for (int i = 0; i < 8; i++)
        GLOAD_LDS16(kg + t + i*128, &Kl[0][t + i*128]);
    __syncthreads();

    for (int it = 0; it < 32; it++){
        int cur = it & 1;
        if (it < 31){
            const uint4* kg2 = kg + (it+1)*1024;
            #pragma unroll
            for (int i = 0; i < 8; i++)
                GLOAD_LDS16(kg2 + t + i*128, &Kl[cur^1][t + i*128]);
        }
        // V fragments nb0/nb1 for this iter (direct from global/L2)
        const uint4* vgi = vg + it*1024 + lane;
        uint4 vf[8];
        #pragma unroll
        for (int f = 0; f < 8; f++) vf[f] = vgi[f*64];

        // S' = K·Q^T : D[kt][qr]
        f32x16 S0, S1;
        #pragma unroll
        for (int r = 0; r < 16; r++){ S0[r]=0.f; S1[r]=0.f; }
        #pragma unroll
        for (int ks = 0; ks < 8; ks++){
            bf16x8 qv = as_bf8(qf[ks]);
            S0 = __builtin_amdgcn_mfma_f32_32x32x16_bf16(as_bf8(Kl[cur][(ks<<6) + lane]),     qv, S0, 0,0,0);
            S1 = __builtin_amdgcn_mfma_f32_32x32x16_bf16(as_bf8(Kl[cur][((8+ks)<<6) + lane]), qv, S1, 0,0,0);
        }

        // softmax (fixed offset, no running max); P -> per-wave LDS in A-frag order
        float psum = 0.f;
        #pragma unroll
        for (int q = 0; q < 4; q++){
            float e0 = __expf(__fmaf_rn(S0[q*4+0], SC, -8.f));
            float e1 = __expf(__fmaf_rn(S0[q*4+1], SC, -8.f));
            float e2 = __expf(__fmaf_rn(S0[q*4+2], SC, -8.f));
            float e3 = __expf(__fmaf_rn(S0[q*4+3], SC, -8.f));
            psum += (e0+e1)+(e2+e3);
            int slot = ((q>>1)<<6) + (lane&31) + ((q&1)<<5);
            *(uint2*)((char*)&Pl[wv][slot] + ((lane>>5)<<3)) = make_uint2(pack2(e0,e1), pack2(e2,e3));
        }
        #pragma unroll
        for (int q = 0; q < 4; q++){
            float e0 = __expf(__fmaf_rn(S1[q*4+0], SC, -8.f));
            float e1 = __expf(__fmaf_rn(S1[q*4+1], SC, -8.f));
            float e2 = __expf(__fmaf_rn(S1[q*4+2], SC, -8.f));
            float e3 = __expf(__fmaf_rn(S1[q*4+3], SC, -8.f));
            psum += (e0+e1)+(e2+e3);
            int slot = ((2 + (q>>1))<<6) + (lane&31) + ((q&1)<<5);
            *(uint2*)((char*)&Pl[wv][slot] + ((lane>>5)<<3)) = make_uint2(pack2(e0,e1), pack2(e2,e3));
        }
        psum += __shfl_xor(psum, 32);
        l_i += psum;

        // V fragments nb2/nb3 (loads overlap PV of nb0/nb1)
        uint4 vf2[8];
        #pragma unroll
        for (int f = 0; f < 8; f++) vf2[f] = vgi[(8+f)*64];

        // PV: O[qr][c] += P·V
        #pragma unroll
        for (int ks = 0; ks < 4; ks++){
            bf16x8 pa = as_bf8(Pl[wv][(ks<<6) + lane]);
            O0 = __builtin_amdgcn_mfma_f32_32x32x16_bf16(pa, as_bf8(vf[ks]),    O0, 0,0,0);
            O1 = __builtin_amdgcn_mfma_f32_32x32x16_bf16(pa, as_bf8(vf[4+ks]),  O1, 0,0,0);
            O2 = __builtin_amdgcn_mfma_f32_32x32x16_bf16(pa, as_bf8(vf2[ks]),   O2, 0,0,0);
            O3 = __builtin_amdgcn_mfma_f32_32x32x16_bf16(pa, as_bf8(vf2[4+ks]), O3, 0,0,0);
        }
        __syncthreads();   // buffer swap: next tile's DMA drained, this tile's reads done
    }

    if (lane < 32) lsum[((size_t)(ksp*4 + b))*HW + qb*32 + lane] = l_i;

    u16* ob = Opart + (((size_t)(ksp*4 + b))*HW + qb*32)*NC;
    #pragma unroll
    for (int r = 0; r < 16; r++){
        int qr = (r&3) + 8*(r>>2) + 4*(lane>>5);
        int c  = lane & 31;
        ob[qr*NC +      c] = f2bf(O0[r]);
        ob[qr*NC + 32 + c] = f2bf(O1[r]);
        ob[qr*NC + 64 + c] = f2bf(O2[r]);
        ob[qr*NC + 96 + c] = f2bf(O3[r]);
    }
}

// ---------------- K3b: combine the 2 K-split partials ----------------
// grid 1024 x 256. out = (O_0 + O_1) / (l_0 + l_1), token-major bf16.
__global__ __launch_bounds__(256) void combine_kernel(const u16* __restrict__ Op,
                                                      const float* __restrict__ lsum,
                                                      u16* __restrict__ ao){
    int idx = blockIdx.x*256 + threadIdx.x;
    int row = idx >> 4, cg = idx & 15;
    float inv = 1.f / (lsum[row] + lsum[16384 + row]);
    uint4 u0 = *(const uint4*)(Op + (size_t)row*NC + cg*8);
    uint4 u1 = *(const uint4*)(Op + (size_t)2097152 + (size_t)row*NC + cg*8);
    float v0[8], v1[8];
    unpack8(u0, v0); unpack8(u1, v1);
    u32 pk[4];
    #pragma unroll
    for (int j = 0; j < 4; j++){
        float r0 = (v0[2*j]   + v1[2*j])   * inv;
        float r1 = (v0[2*j+1] + v1[2*j+1]) * inv;
        pk[j] = (u32)f2bf(r0) | ((u32)f2bf(r1) << 16);
    }
    *(uint4*)(ao + (size_t)row*NC + cg*8) = make_uint4(pk[0],pk[1],pk[2],pk[3]);
}

// ---------------- K4: proj + bias + residual (fp32 out) ----------------
__global__ __launch_bounds__(256) void proj_kernel(const u16* __restrict__ ao,
                                                   const float* __restrict__ w,
                                                   const float* __restrict__ bias,
                                                   const float* __restrict__ x,
                                                   float* __restrict__ out){
    int n0 = blockIdx.x * 32;
    int o0 = blockIdx.y * 64;
    int b  = blockIdx.z;
    __shared__ float Wt[64][132];
    __shared__ float At[32][132];
    int t = threadIdx.x;

    const float4* w4 = (const float4*)(w + (size_t)o0 * NC);
    #pragma unroll
    for (int i = 0; i < 8; i++){
        int f = t + i*256;
        int o = f >> 5, c4 = f & 31;
        *(float4*)&Wt[o][c4*4] = w4[f];
    }
    const u16* aob = ao + ((size_t)b*HW + n0) * NC;
    #pragma unroll
    for (int i = 0; i < 2; i++){
        int f = t + i*256;
        int n = f >> 4, c8 = f & 15;
        uint4 u = *(const uint4*)(aob + (size_t)n*NC + c8*8);
        float v[8]; unpack8(u, v);
        *(float4*)&At[n][c8*8]   = make_float4(v[0],v[1],v[2],v[3]);
        *(float4*)&At[n][c8*8+4] = make_float4(v[4],v[5],v[6],v[7]);
    }
    __syncthreads();

    int to = t >> 4, tn = t & 15;
    float acc[4][2] = {};
    for (int c = 0; c < 128; c++){
        float wvv[4], xv[2];
        #pragma unroll
        for (int i = 0; i < 4; i++) wvv[i] = Wt[to + i*16][c];
        #pragma unroll
        for (int j = 0; j < 2; j++) xv[j] = At[tn + j*16][c];
        #pragma unroll
        for (int i = 0; i < 4; i++)
            #pragma unroll
            for (int j = 0; j < 2; j++) acc[i][j] += wvv[i]*xv[j];
    }
    #pragma unroll
    for (int i = 0; i < 4; i++){
        int o = o0 + to + i*16;
        float bo = bias[o];
        #pragma unroll
        for (int j = 0; j < 2; j++){
            size_t idx = ((size_t)b*NC + o)*HW + n0 + tn + j*16;
            out[idx] = x[idx] + bo + acc[i][j];
        }
    }
}

extern "C" void kernel_launch(void* const* d_in, const int* in_sizes, int n_in,
                              void* d_out, int out_size, void* d_ws, size_t ws_size,
                              hipStream_t stream){
    const float* x      = (const float*)d_in[0];
    const float* norm_w = (const float*)d_in[1];
    const float* norm_b = (const float*)d_in[2];
    const float* qkv_w  = (const float*)d_in[3];
    const float* qkv_b  = (const float*)d_in[4];
    const float* proj_w = (const float*)d_in[5];
    const float* proj_b = (const float*)d_in[6];
    float* out = (float*)d_out;

    // ws: stats 256B | Qf 4.19MB | Kf 4.19MB | Vf 4.19MB | lsum 128KB  (~12.71MB)
    float* stats = (float*)d_ws;
    u16* Qf = (u16*)((char*)d_ws + 256);
    u16* Kf = (u16*)((char*)d_ws + 256 + 4194304);
    u16* Vf = (u16*)((char*)d_ws + 256 + 8388608);
    float* lsum = (float*)((char*)d_ws + 256 + 12582912);
    u16* ao = Qf;                 // Q retired after attn; combine reuses its space
    u16* Opart = (u16*)d_out;     // 2 bf16 partial chunks = exactly 8.39 MB = d_out

    gn_stats_kernel<<<32, 256, 0, stream>>>(x, stats);
    qkv_kernel<<<dim3(64, 6, 4), 256, 0, stream>>>(x, stats, norm_w, norm_b, qkv_w, qkv_b, Qf, Kf, Vf);
    attn_kernel<<<dim3(64, 2, 4), 128, 0, stream>>>((const uint4*)Qf, (const uint4*)Kf, (const uint4*)Vf, Opart, lsum);
    combine_kernel<<<1024, 256, 0, stream>>>(Opart, lsum, ao);
    proj_kernel<<<dim3(128, 2, 4), 256, 0, stream>>>(ao, proj_w, proj_b, x, out);
}

// Round 6
// 201.705 us; speedup vs baseline: 4.8572x; 1.1273x over previous
//
#include <hip/hip_runtime.h>

typedef unsigned short u16;
typedef unsigned int   u32;

#define HW 4096
#define NC 128

typedef __bf16 bf16x8 __attribute__((ext_vector_type(8)));
typedef float  f32x16 __attribute__((ext_vector_type(16)));

__device__ __forceinline__ bf16x8 as_bf8(uint4 u){
    union { uint4 u; bf16x8 b; } c; c.u = u; return c.b;
}
__device__ __forceinline__ u16 f2bf(float f){
    u32 u = __float_as_uint(f);
    return (u16)((u + 0x7fffu + ((u >> 16) & 1u)) >> 16);
}
__device__ __forceinline__ u32 pack2(float a, float b){
    return ((__float_as_uint(a) + 0x8000u) >> 16) | ((__float_as_uint(b) + 0x8000u) & 0xffff0000u);
}
__device__ __forceinline__ float bf_lo(u32 u){ return __uint_as_float(u << 16); }
__device__ __forceinline__ float bf_hi(u32 u){ return __uint_as_float(u & 0xffff0000u); }
__device__ __forceinline__ void unpack8(uint4 u, float* v){
    v[0]=bf_lo(u.x); v[1]=bf_hi(u.x); v[2]=bf_lo(u.y); v[3]=bf_hi(u.y);
    v[4]=bf_lo(u.z); v[5]=bf_hi(u.z); v[6]=bf_lo(u.w); v[7]=bf_hi(u.w);
}

// async global -> LDS, 16B per lane
#define GLOAD_LDS16(g, l) \
    __builtin_amdgcn_global_load_lds((const __attribute__((address_space(1))) u32*)(const void*)(g), \
                                     (__attribute__((address_space(3))) u32*)(void*)(l), 16, 0, 0)

// ---------------- K0: zero the 64-float stats accumulator ----------------
__global__ void zero_stats_kernel(float* __restrict__ stats){
    if (threadIdx.x < 64) stats[threadIdx.x] = 0.f;
}

// ---------------- K1: GroupNorm partial sums. grid=256 (bg*8+part), block=256 ----------------
__global__ __launch_bounds__(256) void gn_stats_kernel(const float* __restrict__ x,
                                                       float* __restrict__ stats){
    int bg = blockIdx.x >> 3, part = blockIdx.x & 7;
    const float4* p = (const float4*)(x + (size_t)bg * 65536 + part * 8192);
    float s = 0.f, ss = 0.f;
    #pragma unroll
    for (int i = 0; i < 8; i++){
        float4 u = p[threadIdx.x + i*256];
        s  += u.x + u.y + u.z + u.w;
        ss += u.x*u.x + u.y*u.y + u.z*u.z + u.w*u.w;
    }
    #pragma unroll
    for (int off = 32; off > 0; off >>= 1){
        s  += __shfl_xor(s,  off);
        ss += __shfl_xor(ss, off);
    }
    __shared__ float rs[4], rss[4];
    int wid = threadIdx.x >> 6;
    if ((threadIdx.x & 63) == 0){ rs[wid] = s; rss[wid] = ss; }
    __syncthreads();
    if (threadIdx.x == 0){
        atomicAdd(&stats[bg*2],   rs[0]+rs[1]+rs[2]+rs[3]);
        atomicAdd(&stats[bg*2+1], rss[0]+rss[1]+rss[2]+rss[3]);
    }
}

// ---------------- K2: fused GN-apply + QKV GEMM, outputs in MFMA-fragment order ----------------
// Q/K: [b][blk32][ks(8)][slot(64)] x 8ch-uint4 : slot l = channels ks*16+(l>>5)*8.. of row blk*32+(l&31)
// V  : [b][it(64)][nb(4)][ks(4)][slot(64)] x 8tok : slot l = tokens it*64+ks*16+(l>>5)*8.. of ch nb*32+(l&31)
__global__ __launch_bounds__(256) void qkv_kernel(const float* __restrict__ x,
                                                  const float* __restrict__ stats,
                                                  const float* __restrict__ gamma,
                                                  const float* __restrict__ beta,
                                                  const float* __restrict__ w,
                                                  const float* __restrict__ bias,
                                                  u16* __restrict__ Qf,
                                                  u16* __restrict__ Kf,
                                                  u16* __restrict__ Vf){
    int n0 = blockIdx.x * 64;
    int o0 = blockIdx.y * 64;
    int b  = blockIdx.z;
    __shared__ float Wt[64][128];
    __shared__ float Xt[128][64];
    int t = threadIdx.x;

    const float4* w4 = (const float4*)(w + (size_t)o0 * NC);
    #pragma unroll
    for (int i = 0; i < 8; i++){
        int f = t + i*256;
        int o = f >> 5, c4 = f & 31;
        *(float4*)&Wt[o][c4*4] = w4[f];
    }
    #pragma unroll
    for (int i = 0; i < 8; i++){
        int f = t + i*256;
        int c = f >> 4, m4 = f & 15;
        float4 u = *(const float4*)(x + ((size_t)b*NC + c)*HW + n0 + m4*4);
        float S  = stats[(b*8 + (c>>4))*2];
        float SS = stats[(b*8 + (c>>4))*2 + 1];
        float mean = S * (1.f/65536.f);
        float rstd = rsqrtf(SS * (1.f/65536.f) - mean*mean + 1e-5f);
        float ga = gamma[c] * rstd;
        float be = beta[c] - mean * ga;
        u.x = u.x*ga + be; u.y = u.y*ga + be; u.z = u.z*ga + be; u.w = u.w*ga + be;
        *(float4*)&Xt[c][m4*4] = u;
    }
    __syncthreads();

    int lane = t & 63, wid = t >> 6;   // wave owns 16 o-rows, lane = token
    float acc[16] = {};
    for (int c4 = 0; c4 < 32; c4++){
        float xv[4];
        #pragma unroll
        for (int k = 0; k < 4; k++) xv[k] = Xt[c4*4+k][lane];
        #pragma unroll
        for (int i = 0; i < 16; i++){
            float4 wv = *(float4*)&Wt[wid*16 + i][c4*4];
            acc[i] += wv.x*xv[0] + wv.y*xv[1] + wv.z*xv[2] + wv.w*xv[3];
        }
    }
    int y = blockIdx.y;
    if (y < 4){
        u16* dst = (y < 2) ? Qf : Kf;
        int o0r = (y < 2) ? o0 : (o0 - 128);
        int ks = (o0r >> 4) + wid;           // thread's 16 channels = one ks
        u32 pk[8];
        #pragma unroll
        for (int j = 0; j < 8; j++){
            float a0 = acc[2*j]   + bias[o0 + wid*16 + 2*j];
            float a1 = acc[2*j+1] + bias[o0 + wid*16 + 2*j+1];
            pk[j] = (u32)f2bf(a0) | ((u32)f2bf(a1) << 16);
        }
        size_t fi = (((size_t)b*128 + (n0>>5) + (lane>>5))*8 + ks)*64 + (lane&31);
        uint4* d4 = (uint4*)dst + fi;
        d4[0]  = make_uint4(pk[0],pk[1],pk[2],pk[3]);   // channel half 0
        d4[32] = make_uint4(pk[4],pk[5],pk[6],pk[7]);   // channel half 1
    } else {
        int c0 = o0 - 256 + wid*16;
        int tok = n0 + lane;
        int nb = c0 >> 5, cl = c0 & 31;
        size_t base = ((((size_t)b*64 + (tok>>6))*4 + nb)*4 + ((tok>>4)&3))*64
                      + (((tok>>3)&1)<<5) + cl;
        u16* d = Vf + base*8 + (tok&7);
        #pragma unroll
        for (int i = 0; i < 16; i++)
            d[i*8] = f2bf(acc[i] + bias[o0 + wid*16 + i]);
    }
}

// ---------------- K3: MFMA flash attention ----------------
// grid 256 (pair = b*2+ksp = blockIdx.x&7 for XCD locality, qx = blockIdx.x>>3),
// block 256 = 4 waves x 32 qrows (TQ=128). TK=64, 32 iters.
// K,V: async DMA -> shared dbuf LDS (64 KB), 1 barrier/iter. P: in-register shuffle exchange.
__global__ __launch_bounds__(256) void attn_kernel(const uint4* __restrict__ Qf,
                                                   const uint4* __restrict__ Kf,
                                                   const uint4* __restrict__ Vf,
                                                   u16* __restrict__ Opart,
                                                   float* __restrict__ lsum){
    int pair = blockIdx.x & 7, qx = blockIdx.x >> 3;
    int b = pair >> 1, ksp = pair & 1;
    int t = threadIdx.x, lane = t & 63, wv = t >> 6;
    int qb = qx*4 + wv;                      // 32-row q-block of this wave (0..127)
    __shared__ uint4 Kl[2][1024];            // dbuf K tile, frag order (32 KB)
    __shared__ uint4 Vl[2][1024];            // dbuf V tile, frag order (32 KB)
    const float SC = 0.08838834764831845f;   // 1/sqrt(128)

    uint4 qf[8];
    const uint4* qptr = Qf + ((size_t)b*128 + qb)*512 + lane;
    #pragma unroll
    for (int ks = 0; ks < 8; ks++) qf[ks] = qptr[ks*64];

    f32x16 O0, O1, O2, O3;
    #pragma unroll
    for (int r = 0; r < 16; r++){ O0[r]=0.f; O1[r]=0.f; O2[r]=0.f; O3[r]=0.f; }
    float l_i = 0.f;

    const uint4* kg = Kf + ((size_t)b*128 + ksp*64)*512;    // 1024 uint4 per iter
    const uint4* vg = Vf + ((size_t)b*64  + ksp*32)*1024;

    // prologue: DMA iter-0 K,V tiles into buffer 0 (256 thr x 16B x 4 = 16 KB each)
    #pragma unroll
    for (int i = 0; i < 4; i++){
        GLOAD_LDS16(kg + t + i*256, &Kl[0][t + i*256]);
        GLOAD_LDS16(vg + t + i*256, &Vl[0][t + i*256]);
    }
    __syncthreads();

    for (int it = 0; it < 32; it++){
        int cur = it & 1;
        if (it < 31){
            const uint4* kg2 = kg + (it+1)*1024;
            const uint4* vg2 = vg + (it+1)*1024;
            #pragma unroll
            for (int i = 0; i < 4; i++){
                GLOAD_LDS16(kg2 + t + i*256, &Kl[cur^1][t + i*256]);
                GLOAD_LDS16(vg2 + t + i*256, &Vl[cur^1][t + i*256]);
            }
        }

        // S' = K·Q^T : D[kt][qr], qr = lane&31 (C-layout col)
        f32x16 S0, S1;
        #pragma unroll
        for (int r = 0; r < 16; r++){ S0[r]=0.f; S1[r]=0.f; }
        #pragma unroll
        for (int ks = 0; ks < 8; ks++){
            bf16x8 qv = as_bf8(qf[ks]);
            S0 = __builtin_amdgcn_mfma_f32_32x32x16_bf16(as_bf8(Kl[cur][(ks<<6) + lane]),     qv, S0, 0,0,0);
            S1 = __builtin_amdgcn_mfma_f32_32x32x16_bf16(as_bf8(Kl[cur][((8+ks)<<6) + lane]), qv, S1, 0,0,0);
        }

        // softmax (fixed offset, no running max). Quad g of S-block holds
        // kt = 8g + 4*(lane>>5) + {0..3}; pack each quad to 2 u32 of bf16.
        float psum = 0.f;
        u32 pk0[8], pk1[8];
        #pragma unroll
        for (int q = 0; q < 4; q++){
            float a0 = __expf(__fmaf_rn(S0[q*4+0], SC, -8.f));
            float a1 = __expf(__fmaf_rn(S0[q*4+1], SC, -8.f));
            float a2 = __expf(__fmaf_rn(S0[q*4+2], SC, -8.f));
            float a3 = __expf(__fmaf_rn(S0[q*4+3], SC, -8.f));
            float b0 = __expf(__fmaf_rn(S1[q*4+0], SC, -8.f));
            float b1 = __expf(__fmaf_rn(S1[q*4+1], SC, -8.f));
            float b2 = __expf(__fmaf_rn(S1[q*4+2], SC, -8.f));
            float b3 = __expf(__fmaf_rn(S1[q*4+3], SC, -8.f));
            psum += ((a0+a1)+(a2+a3)) + ((b0+b1)+(b2+b3));
            pk0[2*q] = pack2(a0,a1); pk0[2*q+1] = pack2(a2,a3);
            pk1[2*q] = pack2(b0,b1); pk1[2*q+1] = pack2(b2,b3);
        }
        psum += __shfl_xor(psum, 32);
        l_i += psum;

        // exchange halves: lane l <-> l^32, build A-fragments of P.
        // frag(ks even pairs): lower half = [own quad(2k), partner quad(2k)],
        //                      upper half = [partner quad(2k+1), own quad(2k+1)]
        u32 x0[8], x1[8];
        #pragma unroll
        for (int i = 0; i < 8; i++){ x0[i] = __shfl_xor(pk0[i], 32); x1[i] = __shfl_xor(pk1[i], 32); }
        bool up = (lane >= 32);
        uint4 fr[4];
        fr[0] = up ? make_uint4(x0[2],x0[3],pk0[2],pk0[3]) : make_uint4(pk0[0],pk0[1],x0[0],x0[1]);
        fr[1] = up ? make_uint4(x0[6],x0[7],pk0[6],pk0[7]) : make_uint4(pk0[4],pk0[5],x0[4],x0[5]);
        fr[2] = up ? make_uint4(x1[2],x1[3],pk1[2],pk1[3]) : make_uint4(pk1[0],pk1[1],x1[0],x1[1]);
        fr[3] = up ? make_uint4(x1[6],x1[7],pk1[6],pk1[7]) : make_uint4(pk1[4],pk1[5],x1[4],x1[5]);

        // PV: O[qr][c] += P·V
        #pragma unroll
        for (int ks = 0; ks < 4; ks++){
            bf16x8 pa = as_bf8(fr[ks]);
            O0 = __builtin_amdgcn_mfma_f32_32x32x16_bf16(pa, as_bf8(Vl[cur][((0*4+ks)<<6) + lane]), O0, 0,0,0);
            O1 = __builtin_amdgcn_mfma_f32_32x32x16_bf16(pa, as_bf8(Vl[cur][((1*4+ks)<<6) + lane]), O1, 0,0,0);
            O2 = __builtin_amdgcn_mfma_f32_32x32x16_bf16(pa, as_bf8(Vl[cur][((2*4+ks)<<6) + lane]), O2, 0,0,0);
            O3 = __builtin_amdgcn_mfma_f32_32x32x16_bf16(pa, as_bf8(Vl[cur][((3*4+ks)<<6) + lane]), O3, 0,0,0);
        }
        __syncthreads();   // next tile's DMA drained; this tile's reads done
    }

    if (lane < 32) lsum[((size_t)(ksp*4 + b))*HW + qb*32 + lane] = l_i;

    u16* ob = Opart + (((size_t)(ksp*4 + b))*HW + qb*32)*NC;
    #pragma unroll
    for (int r = 0; r < 16; r++){
        int qr = (r&3) + 8*(r>>2) + 4*(lane>>5);
        int c  = lane & 31;
        ob[qr*NC +      c] = f2bf(O0[r]);
        ob[qr*NC + 32 + c] = f2bf(O1[r]);
        ob[qr*NC + 64 + c] = f2bf(O2[r]);
        ob[qr*NC + 96 + c] = f2bf(O3[r]);
    }
}

// ---------------- K3b: combine the 2 K-split partials ----------------
// grid 1024 x 256. out = (O_0 + O_1) / (l_0 + l_1), token-major bf16.
__global__ __launch_bounds__(256) void combine_kernel(const u16* __restrict__ Op,
                                                      const float* __restrict__ lsum,
                                                      u16* __restrict__ ao){
    int idx = blockIdx.x*256 + threadIdx.x;
    int row = idx >> 4, cg = idx & 15;
    float inv = 1.f / (lsum[row] + lsum[16384 + row]);
    uint4 u0 = *(const uint4*)(Op + (size_t)row*NC + cg*8);
    uint4 u1 = *(const uint4*)(Op + (size_t)2097152 + (size_t)row*NC + cg*8);
    float v0[8], v1[8];
    unpack8(u0, v0); unpack8(u1, v1);
    u32 pk[4];
    #pragma unroll
    for (int j = 0; j < 4; j++){
        float r0 = (v0[2*j]   + v1[2*j])   * inv;
        float r1 = (v0[2*j+1] + v1[2*j+1]) * inv;
        pk[j] = (u32)f2bf(r0) | ((u32)f2bf(r1) << 16);
    }
    *(uint4*)(ao + (size_t)row*NC + cg*8) = make_uint4(pk[0],pk[1],pk[2],pk[3]);
}

// ---------------- K4: proj + bias + residual (fp32 out) ----------------
__global__ __launch_bounds__(256) void proj_kernel(const u16* __restrict__ ao,
                                                   const float* __restrict__ w,
                                                   const float* __restrict__ bias,
                                                   const float* __restrict__ x,
                                                   float* __restrict__ out){
    int n0 = blockIdx.x * 32;
    int o0 = blockIdx.y * 64;
    int b  = blockIdx.z;
    __shared__ float Wt[64][132];
    __shared__ float At[32][132];
    int t = threadIdx.x;

    const float4* w4 = (const float4*)(w + (size_t)o0 * NC);
    #pragma unroll
    for (int i = 0; i < 8; i++){
        int f = t + i*256;
        int o = f >> 5, c4 = f & 31;
        *(float4*)&Wt[o][c4*4] = w4[f];
    }
    const u16* aob = ao + ((size_t)b*HW + n0) * NC;
    #pragma unroll
    for (int i = 0; i < 2; i++){
        int f = t + i*256;
        int n = f >> 4, c8 = f & 15;
        uint4 u = *(const uint4*)(aob + (size_t)n*NC + c8*8);
        float v[8]; unpack8(u, v);
        *(float4*)&At[n][c8*8]   = make_float4(v[0],v[1],v[2],v[3]);
        *(float4*)&At[n][c8*8+4] = make_float4(v[4],v[5],v[6],v[7]);
    }
    __syncthreads();

    int to = t >> 4, tn = t & 15;
    float acc[4][2] = {};
    for (int c = 0; c < 128; c++){
        float wvv[4], xv[2];
        #pragma unroll
        for (int i = 0; i < 4; i++) wvv[i] = Wt[to + i*16][c];
        #pragma unroll
        for (int j = 0; j < 2; j++) xv[j] = At[tn + j*16][c];
        #pragma unroll
        for (int i = 0; i < 4; i++)
            #pragma unroll
            for (int j = 0; j < 2; j++) acc[i][j] += wvv[i]*xv[j];
    }
    #pragma unroll
    for (int i = 0; i < 4; i++){
        int o = o0 + to + i*16;
        float bo = bias[o];
        #pragma unroll
        for (int j = 0; j < 2; j++){
            size_t idx = ((size_t)b*NC + o)*HW + n0 + tn + j*16;
            out[idx] = x[idx] + bo + acc[i][j];
        }
    }
}

extern "C" void kernel_launch(void* const* d_in, const int* in_sizes, int n_in,
                              void* d_out, int out_size, void* d_ws, size_t ws_size,
                              hipStream_t stream){
    const float* x      = (const float*)d_in[0];
    const float* norm_w = (const float*)d_in[1];
    const float* norm_b = (const float*)d_in[2];
    const float* qkv_w  = (const float*)d_in[3];
    const float* qkv_b  = (const float*)d_in[4];
    const float* proj_w = (const float*)d_in[5];
    const float* proj_b = (const float*)d_in[6];
    float* out = (float*)d_out;

    // ws: stats 256B | Qf 4.19MB | Kf 4.19MB | Vf 4.19MB | lsum 128KB  (~12.71MB)
    float* stats = (float*)d_ws;
    u16* Qf = (u16*)((char*)d_ws + 256);
    u16* Kf = (u16*)((char*)d_ws + 256 + 4194304);
    u16* Vf = (u16*)((char*)d_ws + 256 + 8388608);
    float* lsum = (float*)((char*)d_ws + 256 + 12582912);
    u16* ao = Qf;                 // Q retired after attn; combine reuses its space
    u16* Opart = (u16*)d_out;     // 2 bf16 partial chunks = exactly 8.39 MB = d_out

    zero_stats_kernel<<<1, 64, 0, stream>>>(stats);
    gn_stats_kernel<<<256, 256, 0, stream>>>(x, stats);
    qkv_kernel<<<dim3(64, 6, 4), 256, 0, stream>>>(x, stats, norm_w, norm_b, qkv_w, qkv_b, Qf, Kf, Vf);
    attn_kernel<<<256, 256, 0, stream>>>((const uint4*)Qf, (const uint4*)Kf, (const uint4*)Vf, Opart, lsum);
    combine_kernel<<<1024, 256, 0, stream>>>(Opart, lsum, ao);
    proj_kernel<<<dim3(128, 2, 4), 256, 0, stream>>>(ao, proj_w, proj_b, x, out);
}

// Round 7
// 188.749 us; speedup vs baseline: 5.1907x; 1.0686x over previous
//
#include <hip/hip_runtime.h>

typedef unsigned short u16;
typedef unsigned int   u32;

#define HW 4096
#define NC 128

typedef __bf16 bf16x8 __attribute__((ext_vector_type(8)));
typedef float  f32x16 __attribute__((ext_vector_type(16)));

__device__ __forceinline__ bf16x8 as_bf8(uint4 u){
    union { uint4 u; bf16x8 b; } c; c.u = u; return c.b;
}
__device__ __forceinline__ u16 f2bf(float f){
    u32 u = __float_as_uint(f);
    return (u16)((u + 0x7fffu + ((u >> 16) & 1u)) >> 16);
}
__device__ __forceinline__ u32 pack2(float a, float b){
    return ((__float_as_uint(a) + 0x8000u) >> 16) | ((__float_as_uint(b) + 0x8000u) & 0xffff0000u);
}
__device__ __forceinline__ float bf_lo(u32 u){ return __uint_as_float(u << 16); }
__device__ __forceinline__ float bf_hi(u32 u){ return __uint_as_float(u & 0xffff0000u); }
__device__ __forceinline__ void unpack8(uint4 u, float* v){
    v[0]=bf_lo(u.x); v[1]=bf_hi(u.x); v[2]=bf_lo(u.y); v[3]=bf_hi(u.y);
    v[4]=bf_lo(u.z); v[5]=bf_hi(u.z); v[6]=bf_lo(u.w); v[7]=bf_hi(u.w);
}

// async global -> LDS, 16B per lane
#define GLOAD_LDS16(g, l) \
    __builtin_amdgcn_global_load_lds((const __attribute__((address_space(1))) u32*)(const void*)(g), \
                                     (__attribute__((address_space(3))) u32*)(void*)(l), 16, 0, 0)

// ---------------- K1: GroupNorm partial sums. grid=256 (bg*8+part), block=256 ----------------
// Writes stats[bg*16 + part*2] = sum, [+1] = sumsq. No atomics, no zero pass.
__global__ __launch_bounds__(256) void gn_stats_kernel(const float* __restrict__ x,
                                                       float* __restrict__ stats){
    int bg = blockIdx.x >> 3, part = blockIdx.x & 7;
    const float4* p = (const float4*)(x + (size_t)bg * 65536 + part * 8192);
    float s = 0.f, ss = 0.f;
    #pragma unroll
    for (int i = 0; i < 8; i++){
        float4 u = p[threadIdx.x + i*256];
        s  += u.x + u.y + u.z + u.w;
        ss += u.x*u.x + u.y*u.y + u.z*u.z + u.w*u.w;
    }
    #pragma unroll
    for (int off = 32; off > 0; off >>= 1){
        s  += __shfl_xor(s,  off);
        ss += __shfl_xor(ss, off);
    }
    __shared__ float rs[4], rss[4];
    int wid = threadIdx.x >> 6;
    if ((threadIdx.x & 63) == 0){ rs[wid] = s; rss[wid] = ss; }
    __syncthreads();
    if (threadIdx.x == 0){
        stats[bg*16 + part*2]     = rs[0]+rs[1]+rs[2]+rs[3];
        stats[bg*16 + part*2 + 1] = rss[0]+rss[1]+rss[2]+rss[3];
    }
}

// ---------------- K2: fused GN-apply + QKV GEMM, outputs in MFMA-fragment order ----------------
// Q/K: [b][blk32][ks(8)][slot(64)] x 8ch-uint4 : slot l = channels ks*16+(l>>5)*8.. of row blk*32+(l&31)
// V  : [b][it(64)][nb(4)][ks(4)][slot(64)] x 8tok : slot l = tokens it*64+ks*16+(l>>5)*8.. of ch nb*32+(l&31)
__global__ __launch_bounds__(256) void qkv_kernel(const float* __restrict__ x,
                                                  const float* __restrict__ stats,
                                                  const float* __restrict__ gamma,
                                                  const float* __restrict__ beta,
                                                  const float* __restrict__ w,
                                                  const float* __restrict__ bias,
                                                  u16* __restrict__ Qf,
                                                  u16* __restrict__ Kf,
                                                  u16* __restrict__ Vf){
    int n0 = blockIdx.x * 64;
    int o0 = blockIdx.y * 64;
    int b  = blockIdx.z;
    __shared__ float Wt[64][128];
    __shared__ float Xt[128][64];
    __shared__ float gmean[8], grstd[8];
    int t = threadIdx.x;

    if (t < 8){
        float S = 0.f, SS = 0.f;
        #pragma unroll
        for (int p = 0; p < 8; p++){
            S  += stats[(b*8 + t)*16 + p*2];
            SS += stats[(b*8 + t)*16 + p*2 + 1];
        }
        float mean = S * (1.f/65536.f);
        gmean[t] = mean;
        grstd[t] = rsqrtf(SS * (1.f/65536.f) - mean*mean + 1e-5f);
    }
    __syncthreads();

    const float4* w4 = (const float4*)(w + (size_t)o0 * NC);
    #pragma unroll
    for (int i = 0; i < 8; i++){
        int f = t + i*256;
        int o = f >> 5, c4 = f & 31;
        *(float4*)&Wt[o][c4*4] = w4[f];
    }
    #pragma unroll
    for (int i = 0; i < 8; i++){
        int f = t + i*256;
        int c = f >> 4, m4 = f & 15;
        float4 u = *(const float4*)(x + ((size_t)b*NC + c)*HW + n0 + m4*4);
        float ga = gamma[c] * grstd[c>>4];
        float be = beta[c] - gmean[c>>4] * ga;
        u.x = u.x*ga + be; u.y = u.y*ga + be; u.z = u.z*ga + be; u.w = u.w*ga + be;
        *(float4*)&Xt[c][m4*4] = u;
    }
    __syncthreads();

    int lane = t & 63, wid = t >> 6;   // wave owns 16 o-rows, lane = token
    float acc[16] = {};
    for (int c4 = 0; c4 < 32; c4++){
        float xv[4];
        #pragma unroll
        for (int k = 0; k < 4; k++) xv[k] = Xt[c4*4+k][lane];
        #pragma unroll
        for (int i = 0; i < 16; i++){
            float4 wv = *(float4*)&Wt[wid*16 + i][c4*4];
            acc[i] += wv.x*xv[0] + wv.y*xv[1] + wv.z*xv[2] + wv.w*xv[3];
        }
    }
    int y = blockIdx.y;
    if (y < 4){
        u16* dst = (y < 2) ? Qf : Kf;
        int o0r = (y < 2) ? o0 : (o0 - 128);
        int ks = (o0r >> 4) + wid;           // thread's 16 channels = one ks
        u32 pk[8];
        #pragma unroll
        for (int j = 0; j < 8; j++){
            float a0 = acc[2*j]   + bias[o0 + wid*16 + 2*j];
            float a1 = acc[2*j+1] + bias[o0 + wid*16 + 2*j+1];
            pk[j] = (u32)f2bf(a0) | ((u32)f2bf(a1) << 16);
        }
        size_t fi = (((size_t)b*128 + (n0>>5) + (lane>>5))*8 + ks)*64 + (lane&31);
        uint4* d4 = (uint4*)dst + fi;
        d4[0]  = make_uint4(pk[0],pk[1],pk[2],pk[3]);   // channel half 0
        d4[32] = make_uint4(pk[4],pk[5],pk[6],pk[7]);   // channel half 1
    } else {
        int c0 = o0 - 256 + wid*16;
        int tok = n0 + lane;
        int nb = c0 >> 5, cl = c0 & 31;
        size_t base = ((((size_t)b*64 + (tok>>6))*4 + nb)*4 + ((tok>>4)&3))*64
                      + (((tok>>3)&1)<<5) + cl;
        u16* d = Vf + base*8 + (tok&7);
        #pragma unroll
        for (int i = 0; i < 16; i++)
            d[i*8] = f2bf(acc[i] + bias[o0 + wid*16 + i]);
    }
}

// ---------------- K3: MFMA flash attention, wave = (q-half, k-half) ----------------
// grid 512 (pair = blockIdx.x&7 -> (b,ksp); qx = blockIdx.x>>3, 64 q-tiles of 64 rows),
// block 256 = 4 waves: wave (qh=wv>>1, kh=wv&1) does 32 qrows x 32 ktokens per iter.
// Fixed-offset softmax -> no cross-kh coupling until the final O/l reduce in LDS.
__global__ __launch_bounds__(256, 2) void attn_kernel(const uint4* __restrict__ Qf,
                                                      const uint4* __restrict__ Kf,
                                                      const uint4* __restrict__ Vf,
                                                      u16* __restrict__ Opart,
                                                      float* __restrict__ lsum){
    __shared__ uint4 smem[4096];   // [0..2047] K dbuf, [2048..4095] V dbuf (64 KB)
    int pair = blockIdx.x & 7, qx = blockIdx.x >> 3;
    int b = pair >> 1, ksp = pair & 1;
    int t = threadIdx.x, lane = t & 63, wv = t >> 6;
    int qh = wv >> 1, kh = wv & 1;
    const float SC = 0.08838834764831845f;   // 1/sqrt(128)

    uint4 qf[8];
    const uint4* qptr = Qf + ((size_t)b*128 + qx*2 + qh)*512 + lane;
    #pragma unroll
    for (int ks = 0; ks < 8; ks++) qf[ks] = qptr[ks*64];

    f32x16 O0, O1, O2, O3;
    #pragma unroll
    for (int r = 0; r < 16; r++){ O0[r]=0.f; O1[r]=0.f; O2[r]=0.f; O3[r]=0.f; }
    float l_i = 0.f;

    const uint4* kg = Kf + ((size_t)b*128 + ksp*64)*512;    // 1024 uint4 per iter
    const uint4* vg = Vf + ((size_t)b*64  + ksp*32)*1024;

    #pragma unroll
    for (int i = 0; i < 4; i++){
        GLOAD_LDS16(kg + t + i*256, &smem[t + i*256]);
        GLOAD_LDS16(vg + t + i*256, &smem[2048 + t + i*256]);
    }
    __syncthreads();

    for (int it = 0; it < 32; it++){
        int cur = it & 1;
        if (it < 31){
            const uint4* kg2 = kg + (it+1)*1024;
            const uint4* vg2 = vg + (it+1)*1024;
            #pragma unroll
            for (int i = 0; i < 4; i++){
                GLOAD_LDS16(kg2 + t + i*256, &smem[(cur^1)*1024 + t + i*256]);
                GLOAD_LDS16(vg2 + t + i*256, &smem[2048 + (cur^1)*1024 + t + i*256]);
            }
        }

        // S' = K·Q^T for this wave's 32 ktokens: D[kt][qr], qr = lane&31
        f32x16 S0;
        #pragma unroll
        for (int r = 0; r < 16; r++) S0[r] = 0.f;
        #pragma unroll
        for (int ks = 0; ks < 8; ks++)
            S0 = __builtin_amdgcn_mfma_f32_32x32x16_bf16(
                     as_bf8(smem[cur*1024 + ((kh*8 + ks)<<6) + lane]),
                     as_bf8(qf[ks]), S0, 0,0,0);

        // softmax (fixed offset -8, no running max)
        float psum = 0.f;
        u32 pk[8];
        #pragma unroll
        for (int q = 0; q < 4; q++){
            float e0 = __expf(__fmaf_rn(S0[q*4+0], SC, -8.f));
            float e1 = __expf(__fmaf_rn(S0[q*4+1], SC, -8.f));
            float e2 = __expf(__fmaf_rn(S0[q*4+2], SC, -8.f));
            float e3 = __expf(__fmaf_rn(S0[q*4+3], SC, -8.f));
            psum += (e0+e1)+(e2+e3);
            pk[2*q] = pack2(e0,e1); pk[2*q+1] = pack2(e2,e3);
        }
        psum += __shfl_xor(psum, 32);
        l_i += psum;

        // half-exchange: build A-fragments of P (k-dim = this wave's 32 tokens)
        u32 xch[8];
        #pragma unroll
        for (int i = 0; i < 8; i++) xch[i] = __shfl_xor(pk[i], 32);
        bool up = (lane >= 32);
        uint4 fr0 = up ? make_uint4(xch[2],xch[3],pk[2],pk[3]) : make_uint4(pk[0],pk[1],xch[0],xch[1]);
        uint4 fr1 = up ? make_uint4(xch[6],xch[7],pk[6],pk[7]) : make_uint4(pk[4],pk[5],xch[4],xch[5]);

        // PV over this wave's k-half: V frag (nb*4 + kh*2 + ks)
        int vb = 2048 + cur*1024 + (kh<<7);
        #pragma unroll
        for (int ks = 0; ks < 2; ks++){
            bf16x8 pa = as_bf8(ks ? fr1 : fr0);
            O0 = __builtin_amdgcn_mfma_f32_32x32x16_bf16(pa, as_bf8(smem[vb +   0 + (ks<<6) + lane]), O0, 0,0,0);
            O1 = __builtin_amdgcn_mfma_f32_32x32x16_bf16(pa, as_bf8(smem[vb + 256 + (ks<<6) + lane]), O1, 0,0,0);
            O2 = __builtin_amdgcn_mfma_f32_32x32x16_bf16(pa, as_bf8(smem[vb + 512 + (ks<<6) + lane]), O2, 0,0,0);
            O3 = __builtin_amdgcn_mfma_f32_32x32x16_bf16(pa, as_bf8(smem[vb + 768 + (ks<<6) + lane]), O3, 0,0,0);
        }
        __syncthreads();   // next tile's DMA drained; this tile's reads done
    }

    // cross-wave (kh) reduce of O and l via LDS
    float* fsm  = (float*)smem;        // 8192 floats = 32 KB
    float* lred = fsm + 8192;          // 64 floats
    if (kh == 1){
        #pragma unroll
        for (int r = 0; r < 16; r++){
            fsm[((qh*4+0)*16 + r)*64 + lane] = O0[r];
            fsm[((qh*4+1)*16 + r)*64 + lane] = O1[r];
            fsm[((qh*4+2)*16 + r)*64 + lane] = O2[r];
            fsm[((qh*4+3)*16 + r)*64 + lane] = O3[r];
        }
        if (lane < 32) lred[qh*32 + lane] = l_i;
    }
    __syncthreads();
    if (kh == 0){
        float lt = l_i + lred[qh*32 + (lane & 31)];
        if (lane < 32) lsum[((size_t)(ksp*4 + b))*HW + qx*64 + qh*32 + lane] = lt;
        u16* ob = Opart + (((size_t)(ksp*4 + b))*HW + qx*64 + qh*32)*NC;
        #pragma unroll
        for (int r = 0; r < 16; r++){
            int qr = (r&3) + 8*(r>>2) + 4*(lane>>5);
            int c  = lane & 31;
            ob[qr*NC +      c] = f2bf(O0[r] + fsm[((qh*4+0)*16 + r)*64 + lane]);
            ob[qr*NC + 32 + c] = f2bf(O1[r] + fsm[((qh*4+1)*16 + r)*64 + lane]);
            ob[qr*NC + 64 + c] = f2bf(O2[r] + fsm[((qh*4+2)*16 + r)*64 + lane]);
            ob[qr*NC + 96 + c] = f2bf(O3[r] + fsm[((qh*4+3)*16 + r)*64 + lane]);
        }
    }
}

// ---------------- K3b: combine the 2 K-split partials ----------------
// grid 1024 x 256. out = (O_0 + O_1) / (l_0 + l_1), token-major bf16.
__global__ __launch_bounds__(256) void combine_kernel(const u16* __restrict__ Op,
                                                      const float* __restrict__ lsum,
                                                      u16* __restrict__ ao){
    int idx = blockIdx.x*256 + threadIdx.x;
    int row = idx >> 4, cg = idx & 15;
    float inv = 1.f / (lsum[row] + lsum[16384 + row]);
    uint4 u0 = *(const uint4*)(Op + (size_t)row*NC + cg*8);
    uint4 u1 = *(const uint4*)(Op + (size_t)2097152 + (size_t)row*NC + cg*8);
    float v0[8], v1[8];
    unpack8(u0, v0); unpack8(u1, v1);
    u32 pk[4];
    #pragma unroll
    for (int j = 0; j < 4; j++){
        float r0 = (v0[2*j]   + v1[2*j])   * inv;
        float r1 = (v0[2*j+1] + v1[2*j+1]) * inv;
        pk[j] = (u32)f2bf(r0) | ((u32)f2bf(r1) << 16);
    }
    *(uint4*)(ao + (size_t)row*NC + cg*8) = make_uint4(pk[0],pk[1],pk[2],pk[3]);
}

// ---------------- K4: proj + bias + residual (fp32 out) ----------------
__global__ __launch_bounds__(256) void proj_kernel(const u16* __restrict__ ao,
                                                   const float* __restrict__ w,
                                                   const float* __restrict__ bias,
                                                   const float* __restrict__ x,
                                                   float* __restrict__ out){
    int n0 = blockIdx.x * 32;
    int o0 = blockIdx.y * 64;
    int b  = blockIdx.z;
    __shared__ float Wt[64][132];
    __shared__ float At[32][132];
    int t = threadIdx.x;

    const float4* w4 = (const float4*)(w + (size_t)o0 * NC);
    #pragma unroll
    for (int i = 0; i < 8; i++){
        int f = t + i*256;
        int o = f >> 5, c4 = f & 31;
        *(float4*)&Wt[o][c4*4] = w4[f];
    }
    const u16* aob = ao + ((size_t)b*HW + n0) * NC;
    #pragma unroll
    for (int i = 0; i < 2; i++){
        int f = t + i*256;
        int n = f >> 4, c8 = f & 15;
        uint4 u = *(const uint4*)(aob + (size_t)n*NC + c8*8);
        float v[8]; unpack8(u, v);
        *(float4*)&At[n][c8*8]   = make_float4(v[0],v[1],v[2],v[3]);
        *(float4*)&At[n][c8*8+4] = make_float4(v[4],v[5],v[6],v[7]);
    }
    __syncthreads();

    int to = t >> 4, tn = t & 15;
    float acc[4][2] = {};
    for (int c = 0; c < 128; c++){
        float wvv[4], xv[2];
        #pragma unroll
        for (int i = 0; i < 4; i++) wvv[i] = Wt[to + i*16][c];
        #pragma unroll
        for (int j = 0; j < 2; j++) xv[j] = At[tn + j*16][c];
        #pragma unroll
        for (int i = 0; i < 4; i++)
            #pragma unroll
            for (int j = 0; j < 2; j++) acc[i][j] += wvv[i]*xv[j];
    }
    #pragma unroll
    for (int i = 0; i < 4; i++){
        int o = o0 + to + i*16;
        float bo = bias[o];
        #pragma unroll
        for (int j = 0; j < 2; j++){
            size_t idx = ((size_t)b*NC + o)*HW + n0 + tn + j*16;
            out[idx] = x[idx] + bo + acc[i][j];
        }
    }
}

extern "C" void kernel_launch(void* const* d_in, const int* in_sizes, int n_in,
                              void* d_out, int out_size, void* d_ws, size_t ws_size,
                              hipStream_t stream){
    const float* x      = (const float*)d_in[0];
    const float* norm_w = (const float*)d_in[1];
    const float* norm_b = (const float*)d_in[2];
    const float* qkv_w  = (const float*)d_in[3];
    const float* qkv_b  = (const float*)d_in[4];
    const float* proj_w = (const float*)d_in[5];
    const float* proj_b = (const float*)d_in[6];
    float* out = (float*)d_out;

    // ws: stats 2KB | Qf 4.19MB | Kf 4.19MB | Vf 4.19MB | lsum 128KB  (~12.72MB)
    float* stats = (float*)d_ws;
    u16* Qf = (u16*)((char*)d_ws + 2048);
    u16* Kf = (u16*)((char*)d_ws + 2048 + 4194304);
    u16* Vf = (u16*)((char*)d_ws + 2048 + 8388608);
    float* lsum = (float*)((char*)d_ws + 2048 + 12582912);
    u16* ao = Qf;                 // Q retired after attn; combine reuses its space
    u16* Opart = (u16*)d_out;     // 2 bf16 partial chunks = exactly 8.39 MB = d_out

    gn_stats_kernel<<<256, 256, 0, stream>>>(x, stats);
    qkv_kernel<<<dim3(64, 6, 4), 256, 0, stream>>>(x, stats, norm_w, norm_b, qkv_w, qkv_b, Qf, Kf, Vf);
    attn_kernel<<<512, 256, 0, stream>>>((const uint4*)Qf, (const uint4*)Kf, (const uint4*)Vf, Opart, lsum);
    combine_kernel<<<1024, 256, 0, stream>>>(Opart, lsum, ao);
    proj_kernel<<<dim3(128, 2, 4), 256, 0, stream>>>(ao, proj_w, proj_b, x, out);
}

// Round 8
// 147.532 us; speedup vs baseline: 6.6408x; 1.2794x over previous
//
#include <hip/hip_runtime.h>

typedef unsigned short u16;
typedef unsigned int   u32;

#define HW 4096
#define NC 128

typedef __bf16 bf16x8 __attribute__((ext_vector_type(8)));
typedef float  f32x16 __attribute__((ext_vector_type(16)));

__device__ __forceinline__ bf16x8 as_bf8(uint4 u){
    union { uint4 u; bf16x8 b; } c; c.u = u; return c.b;
}
__device__ __forceinline__ u16 f2bf(float f){
    u32 u = __float_as_uint(f);
    return (u16)((u + 0x7fffu + ((u >> 16) & 1u)) >> 16);
}
__device__ __forceinline__ u32 pack2(float a, float b){
    return ((__float_as_uint(a) + 0x8000u) >> 16) | ((__float_as_uint(b) + 0x8000u) & 0xffff0000u);
}
__device__ __forceinline__ float bf_lo(u32 u){ return __uint_as_float(u << 16); }
__device__ __forceinline__ float bf_hi(u32 u){ return __uint_as_float(u & 0xffff0000u); }
__device__ __forceinline__ void unpack8(uint4 u, float* v){
    v[0]=bf_lo(u.x); v[1]=bf_hi(u.x); v[2]=bf_lo(u.y); v[3]=bf_hi(u.y);
    v[4]=bf_lo(u.z); v[5]=bf_hi(u.z); v[6]=bf_lo(u.w); v[7]=bf_hi(u.w);
}

// async global -> LDS, 16B per lane
#define GLOAD_LDS16(g, l) \
    __builtin_amdgcn_global_load_lds((const __attribute__((address_space(1))) u32*)(const void*)(g), \
                                     (__attribute__((address_space(3))) u32*)(void*)(l), 16, 0, 0)

// ---------------- K1: GroupNorm partial sums. grid=256 (bg*8+part), block=256 ----------------
__global__ __launch_bounds__(256) void gn_stats_kernel(const float* __restrict__ x,
                                                       float* __restrict__ stats){
    int bg = blockIdx.x >> 3, part = blockIdx.x & 7;
    const float4* p = (const float4*)(x + (size_t)bg * 65536 + part * 8192);
    float s = 0.f, ss = 0.f;
    #pragma unroll
    for (int i = 0; i < 8; i++){
        float4 u = p[threadIdx.x + i*256];
        s  += u.x + u.y + u.z + u.w;
        ss += u.x*u.x + u.y*u.y + u.z*u.z + u.w*u.w;
    }
    #pragma unroll
    for (int off = 32; off > 0; off >>= 1){
        s  += __shfl_xor(s,  off);
        ss += __shfl_xor(ss, off);
    }
    __shared__ float rs[4], rss[4];
    int wid = threadIdx.x >> 6;
    if ((threadIdx.x & 63) == 0){ rs[wid] = s; rss[wid] = ss; }
    __syncthreads();
    if (threadIdx.x == 0){
        stats[bg*16 + part*2]     = rs[0]+rs[1]+rs[2]+rs[3];
        stats[bg*16 + part*2 + 1] = rss[0]+rss[1]+rss[2]+rss[3];
    }
}

// ---------------- K1b: pack qkv_w / proj_w into bf16 A-operand fragments ----------------
// Wf: 12 ob x 8 ks x 64 slots; Pf: 4 ob x 8 ks x 64. slot l: row o = ob*32+(l&31),
// k = ks*16 + (l>>5)*8 + 0..7.  grid 32 x 256.
__global__ __launch_bounds__(256) void wprep_kernel(const float* __restrict__ qkv_w,
                                                    const float* __restrict__ proj_w,
                                                    uint4* __restrict__ Wf,
                                                    uint4* __restrict__ Pf){
    int id = blockIdx.x*256 + threadIdx.x;   // 0..8191
    const float* src; uint4* dst; int fi;
    if (id < 6144){ src = qkv_w; dst = Wf; fi = id; }
    else          { src = proj_w; dst = Pf; fi = id - 6144; }
    int l = fi & 63, ks = (fi >> 6) & 7, ob = fi >> 9;
    int o = ob*32 + (l & 31);
    int c = ks*16 + ((l >> 5) << 3);
    const float* s = src + o*128 + c;
    dst[fi] = make_uint4(pack2(s[0],s[1]), pack2(s[2],s[3]), pack2(s[4],s[5]), pack2(s[6],s[7]));
}

// ---------------- K2: MFMA GN+QKV. grid 512 (b = x>>7, tokblk = x&127), block 256 ----------------
// wave wv handles obs {wv*3, wv*3+1, wv*3+2}; obs 0-3 -> Q, 4-7 -> K, 8-11 -> V.
__global__ __launch_bounds__(256) void qkv_kernel(const float* __restrict__ x,
                                                  const float* __restrict__ stats,
                                                  const float* __restrict__ gamma,
                                                  const float* __restrict__ beta,
                                                  const uint4* __restrict__ Wf,
                                                  const float* __restrict__ bias,
                                                  uint4* __restrict__ Qf,
                                                  uint4* __restrict__ Kf,
                                                  uint4* __restrict__ Vf){
    __shared__ float gaL[128], beL[128], biasL[384];
    int b = blockIdx.x >> 7, tokblk = blockIdx.x & 127;
    int t = threadIdx.x, lane = t & 63, wv = t >> 6;
    if (t < 128){
        int g = t >> 4;
        float S = 0.f, SS = 0.f;
        #pragma unroll
        for (int p = 0; p < 8; p++){
            S  += stats[(b*8 + g)*16 + p*2];
            SS += stats[(b*8 + g)*16 + p*2 + 1];
        }
        float mean = S * (1.f/65536.f);
        float rstd = rsqrtf(SS * (1.f/65536.f) - mean*mean + 1e-5f);
        float ga = gamma[t] * rstd;
        gaL[t] = ga; beL[t] = beta[t] - mean*ga;
    }
    if (t < 192){ biasL[t] = bias[t]; biasL[t+192] = bias[t+192]; }
    __syncthreads();

    int h = lane >> 5, tl = lane & 31;
    // X B-fragments for this block's 32 tokens (GN applied, bf16)
    uint4 xf[8];
    const float* xb = x + (size_t)b*128*HW + tokblk*32 + tl;
    #pragma unroll
    for (int ks = 0; ks < 8; ks++){
        int c0 = ks*16 + h*8;
        float4 g0 = *(float4*)&gaL[c0], g1 = *(float4*)&gaL[c0+4];
        float4 e0 = *(float4*)&beL[c0], e1 = *(float4*)&beL[c0+4];
        float v[8];
        #pragma unroll
        for (int j = 0; j < 8; j++) v[j] = xb[(size_t)(c0+j)*HW];
        v[0] = fmaf(v[0], g0.x, e0.x); v[1] = fmaf(v[1], g0.y, e0.y);
        v[2] = fmaf(v[2], g0.z, e0.z); v[3] = fmaf(v[3], g0.w, e0.w);
        v[4] = fmaf(v[4], g1.x, e1.x); v[5] = fmaf(v[5], g1.y, e1.y);
        v[6] = fmaf(v[6], g1.z, e1.z); v[7] = fmaf(v[7], g1.w, e1.w);
        xf[ks] = make_uint4(pack2(v[0],v[1]), pack2(v[2],v[3]), pack2(v[4],v[5]), pack2(v[6],v[7]));
    }

    bool up = (lane >= 32);
    #pragma unroll
    for (int i = 0; i < 3; i++){
        int ob = wv*3 + i;
        uint4 wf[8];
        #pragma unroll
        for (int ks = 0; ks < 8; ks++) wf[ks] = Wf[(ob*8 + ks)*64 + lane];
        f32x16 D;
        #pragma unroll
        for (int r = 0; r < 16; r++) D[r] = 0.f;
        if (ob < 8){
            // D[o][tok]: col = token
            #pragma unroll
            for (int ks = 0; ks < 8; ks++)
                D = __builtin_amdgcn_mfma_f32_32x32x16_bf16(as_bf8(wf[ks]), as_bf8(xf[ks]), D, 0,0,0);
            #pragma unroll
            for (int r = 0; r < 16; r++)
                D[r] += biasL[ob*32 + (r&3) + 8*(r>>2) + 4*h];
            u32 pk[8], xch[8];
            #pragma unroll
            for (int j = 0; j < 8; j++) pk[j] = pack2(D[2*j], D[2*j+1]);
            #pragma unroll
            for (int j = 0; j < 8; j++) xch[j] = __shfl_xor(pk[j], 32);
            uint4 F0 = up ? make_uint4(xch[2],xch[3],pk[2],pk[3]) : make_uint4(pk[0],pk[1],xch[0],xch[1]);
            uint4 F1 = up ? make_uint4(xch[6],xch[7],pk[6],pk[7]) : make_uint4(pk[4],pk[5],xch[4],xch[5]);
            uint4* dst = (ob < 4) ? Qf : Kf;
            int obl = ob & 3;
            size_t base = (((size_t)b*128 + tokblk)*8 + obl*2)*64 + lane;
            dst[base] = F0; dst[base + 64] = F1;
        } else {
            // V: D[tok][ch]: col = channel
            #pragma unroll
            for (int ks = 0; ks < 8; ks++)
                D = __builtin_amdgcn_mfma_f32_32x32x16_bf16(as_bf8(xf[ks]), as_bf8(wf[ks]), D, 0,0,0);
            int nb = ob - 8;
            float vb = biasL[256 + nb*32 + tl];
            #pragma unroll
            for (int r = 0; r < 16; r++) D[r] += vb;
            u32 pk[8], xch[8];
            #pragma unroll
            for (int j = 0; j < 8; j++) pk[j] = pack2(D[2*j], D[2*j+1]);
            #pragma unroll
            for (int j = 0; j < 8; j++) xch[j] = __shfl_xor(pk[j], 32);
            uint4 F0 = up ? make_uint4(xch[2],xch[3],pk[2],pk[3]) : make_uint4(pk[0],pk[1],xch[0],xch[1]);
            uint4 F1 = up ? make_uint4(xch[6],xch[7],pk[6],pk[7]) : make_uint4(pk[4],pk[5],xch[4],xch[5]);
            int it = tokblk >> 1, t2 = tokblk & 1;
            size_t base = ((((size_t)b*64 + it)*4 + nb)*4 + t2*2)*64 + lane;
            Vf[base] = F0; Vf[base + 64] = F1;
        }
    }
}

// ---------------- K3: MFMA flash attention, wave = (q-half, k-half) ----------------
// grid 512, block 256. (unchanged from round 7 — verified)
__global__ __launch_bounds__(256, 2) void attn_kernel(const uint4* __restrict__ Qf,
                                                      const uint4* __restrict__ Kf,
                                                      const uint4* __restrict__ Vf,
                                                      u16* __restrict__ Opart,
                                                      float* __restrict__ lsum){
    __shared__ uint4 smem[4096];   // [0..2047] K dbuf, [2048..4095] V dbuf (64 KB)
    int pair = blockIdx.x & 7, qx = blockIdx.x >> 3;
    int b = pair >> 1, ksp = pair & 1;
    int t = threadIdx.x, lane = t & 63, wv = t >> 6;
    int qh = wv >> 1, kh = wv & 1;
    const float SC = 0.08838834764831845f;   // 1/sqrt(128)

    uint4 qf[8];
    const uint4* qptr = Qf + ((size_t)b*128 + qx*2 + qh)*512 + lane;
    #pragma unroll
    for (int ks = 0; ks < 8; ks++) qf[ks] = qptr[ks*64];

    f32x16 O0, O1, O2, O3;
    #pragma unroll
    for (int r = 0; r < 16; r++){ O0[r]=0.f; O1[r]=0.f; O2[r]=0.f; O3[r]=0.f; }
    float l_i = 0.f;

    const uint4* kg = Kf + ((size_t)b*128 + ksp*64)*512;
    const uint4* vg = Vf + ((size_t)b*64  + ksp*32)*1024;

    #pragma unroll
    for (int i = 0; i < 4; i++){
        GLOAD_LDS16(kg + t + i*256, &smem[t + i*256]);
        GLOAD_LDS16(vg + t + i*256, &smem[2048 + t + i*256]);
    }
    __syncthreads();

    for (int it = 0; it < 32; it++){
        int cur = it & 1;
        if (it < 31){
            const uint4* kg2 = kg + (it+1)*1024;
            const uint4* vg2 = vg + (it+1)*1024;
            #pragma unroll
            for (int i = 0; i < 4; i++){
                GLOAD_LDS16(kg2 + t + i*256, &smem[(cur^1)*1024 + t + i*256]);
                GLOAD_LDS16(vg2 + t + i*256, &smem[2048 + (cur^1)*1024 + t + i*256]);
            }
        }

        f32x16 S0;
        #pragma unroll
        for (int r = 0; r < 16; r++) S0[r] = 0.f;
        #pragma unroll
        for (int ks = 0; ks < 8; ks++)
            S0 = __builtin_amdgcn_mfma_f32_32x32x16_bf16(
                     as_bf8(smem[cur*1024 + ((kh*8 + ks)<<6) + lane]),
                     as_bf8(qf[ks]), S0, 0,0,0);

        float psum = 0.f;
        u32 pk[8];
        #pragma unroll
        for (int q = 0; q < 4; q++){
            float e0 = __expf(__fmaf_rn(S0[q*4+0], SC, -8.f));
            float e1 = __expf(__fmaf_rn(S0[q*4+1], SC, -8.f));
            float e2 = __expf(__fmaf_rn(S0[q*4+2], SC, -8.f));
            float e3 = __expf(__fmaf_rn(S0[q*4+3], SC, -8.f));
            psum += (e0+e1)+(e2+e3);
            pk[2*q] = pack2(e0,e1); pk[2*q+1] = pack2(e2,e3);
        }
        psum += __shfl_xor(psum, 32);
        l_i += psum;

        u32 xch[8];
        #pragma unroll
        for (int i = 0; i < 8; i++) xch[i] = __shfl_xor(pk[i], 32);
        bool up = (lane >= 32);
        uint4 fr0 = up ? make_uint4(xch[2],xch[3],pk[2],pk[3]) : make_uint4(pk[0],pk[1],xch[0],xch[1]);
        uint4 fr1 = up ? make_uint4(xch[6],xch[7],pk[6],pk[7]) : make_uint4(pk[4],pk[5],xch[4],xch[5]);

        int vb = 2048 + cur*1024 + (kh<<7);
        #pragma unroll
        for (int ks = 0; ks < 2; ks++){
            bf16x8 pa = as_bf8(ks ? fr1 : fr0);
            O0 = __builtin_amdgcn_mfma_f32_32x32x16_bf16(pa, as_bf8(smem[vb +   0 + (ks<<6) + lane]), O0, 0,0,0);
            O1 = __builtin_amdgcn_mfma_f32_32x32x16_bf16(pa, as_bf8(smem[vb + 256 + (ks<<6) + lane]), O1, 0,0,0);
            O2 = __builtin_amdgcn_mfma_f32_32x32x16_bf16(pa, as_bf8(smem[vb + 512 + (ks<<6) + lane]), O2, 0,0,0);
            O3 = __builtin_amdgcn_mfma_f32_32x32x16_bf16(pa, as_bf8(smem[vb + 768 + (ks<<6) + lane]), O3, 0,0,0);
        }
        __syncthreads();
    }

    float* fsm  = (float*)smem;
    float* lred = fsm + 8192;
    if (kh == 1){
        #pragma unroll
        for (int r = 0; r < 16; r++){
            fsm[((qh*4+0)*16 + r)*64 + lane] = O0[r];
            fsm[((qh*4+1)*16 + r)*64 + lane] = O1[r];
            fsm[((qh*4+2)*16 + r)*64 + lane] = O2[r];
            fsm[((qh*4+3)*16 + r)*64 + lane] = O3[r];
        }
        if (lane < 32) lred[qh*32 + lane] = l_i;
    }
    __syncthreads();
    if (kh == 0){
        float lt = l_i + lred[qh*32 + (lane & 31)];
        if (lane < 32) lsum[((size_t)(ksp*4 + b))*HW + qx*64 + qh*32 + lane] = lt;
        u16* ob = Opart + (((size_t)(ksp*4 + b))*HW + qx*64 + qh*32)*NC;
        #pragma unroll
        for (int r = 0; r < 16; r++){
            int qr = (r&3) + 8*(r>>2) + 4*(lane>>5);
            int c  = lane & 31;
            ob[qr*NC +      c] = f2bf(O0[r] + fsm[((qh*4+0)*16 + r)*64 + lane]);
            ob[qr*NC + 32 + c] = f2bf(O1[r] + fsm[((qh*4+1)*16 + r)*64 + lane]);
            ob[qr*NC + 64 + c] = f2bf(O2[r] + fsm[((qh*4+2)*16 + r)*64 + lane]);
            ob[qr*NC + 96 + c] = f2bf(O3[r] + fsm[((qh*4+3)*16 + r)*64 + lane]);
        }
    }
}

// ---------------- K3b: combine K-split partials -> ao in B-fragment order ----------------
// grid 1024 x 256. ao frag uint4 idx = ((row>>5)*8 + cg>>1)*64 + (row&31) + ((cg&1)<<5).
__global__ __launch_bounds__(256) void combine_kernel(const u16* __restrict__ Op,
                                                      const float* __restrict__ lsum,
                                                      uint4* __restrict__ ao){
    int idx = blockIdx.x*256 + threadIdx.x;
    int row = idx >> 4, cg = idx & 15;
    float inv = 1.f / (lsum[row] + lsum[16384 + row]);
    uint4 u0 = *(const uint4*)(Op + (size_t)row*NC + cg*8);
    uint4 u1 = *(const uint4*)(Op + (size_t)2097152 + (size_t)row*NC + cg*8);
    float v0[8], v1[8];
    unpack8(u0, v0); unpack8(u1, v1);
    u32 pk[4];
    #pragma unroll
    for (int j = 0; j < 4; j++){
        float r0 = (v0[2*j]   + v1[2*j])   * inv;
        float r1 = (v0[2*j+1] + v1[2*j+1]) * inv;
        pk[j] = pack2(r0, r1);
    }
    size_t fi = (((size_t)(row >> 5))*8 + (cg >> 1))*64 + (row & 31) + ((cg & 1) << 5);
    ao[fi] = make_uint4(pk[0], pk[1], pk[2], pk[3]);
}

// ---------------- K4: MFMA proj + bias + residual. grid 256, block 256 ----------------
__global__ __launch_bounds__(256) void proj_kernel(const uint4* __restrict__ aof,
                                                   const uint4* __restrict__ Pf,
                                                   const float* __restrict__ bias,
                                                   const float* __restrict__ x,
                                                   float* __restrict__ out){
    __shared__ float biasL[128];
    int t = threadIdx.x, lane = t & 63, wv = t >> 6;
    if (t < 128) biasL[t] = bias[t];
    __syncthreads();
    int b = blockIdx.x >> 6, tk = blockIdx.x & 63;
    int tokb2 = wv & 1, obh = wv >> 1;
    int tokblk = tk*2 + tokb2;
    int h = lane >> 5, tl = lane & 31;

    uint4 af[8];
    const uint4* ab = aof + (((size_t)b*128 + tokblk)*8)*64 + lane;
    #pragma unroll
    for (int ks = 0; ks < 8; ks++) af[ks] = ab[ks*64];

    #pragma unroll
    for (int i = 0; i < 2; i++){
        int ob = obh*2 + i;
        uint4 pf[8];
        #pragma unroll
        for (int ks = 0; ks < 8; ks++) pf[ks] = Pf[(ob*8 + ks)*64 + lane];
        f32x16 D;
        #pragma unroll
        for (int r = 0; r < 16; r++) D[r] = 0.f;
        #pragma unroll
        for (int ks = 0; ks < 8; ks++)
            D = __builtin_amdgcn_mfma_f32_32x32x16_bf16(as_bf8(pf[ks]), as_bf8(af[ks]), D, 0,0,0);
        #pragma unroll
        for (int r = 0; r < 16; r++){
            int o = ob*32 + (r&3) + 8*(r>>2) + 4*h;
            size_t gi = ((size_t)b*128 + o)*HW + tokblk*32 + tl;
            out[gi] = x[gi] + biasL[o] + D[r];
        }
    }
}

extern "C" void kernel_launch(void* const* d_in, const int* in_sizes, int n_in,
                              void* d_out, int out_size, void* d_ws, size_t ws_size,
                              hipStream_t stream){
    const float* x      = (const float*)d_in[0];
    const float* norm_w = (const float*)d_in[1];
    const float* norm_b = (const float*)d_in[2];
    const float* qkv_w  = (const float*)d_in[3];
    const float* qkv_b  = (const float*)d_in[4];
    const float* proj_w = (const float*)d_in[5];
    const float* proj_b = (const float*)d_in[6];
    float* out = (float*)d_out;

    // ws: stats 2KB | Qf 4.19MB | Kf 4.19MB | Vf 4.19MB | lsum 128KB | Wf 96KB | Pf 32KB (~12.85MB)
    char* w = (char*)d_ws;
    float* stats = (float*)w;
    uint4* Qf = (uint4*)(w + 2048);
    uint4* Kf = (uint4*)(w + 2048 + 4194304);
    uint4* Vf = (uint4*)(w + 2048 + 8388608);
    float* lsum = (float*)(w + 2048 + 12582912);
    uint4* Wf = (uint4*)(w + 2048 + 12582912 + 131072);
    uint4* Pf = (uint4*)(w + 2048 + 12582912 + 131072 + 98304);
    uint4* ao = Qf;               // Q retired after attn; combine writes frags here
    u16* Opart = (u16*)d_out;     // 2 bf16 partial chunks = exactly 8.39 MB = d_out

    gn_stats_kernel<<<256, 256, 0, stream>>>(x, stats);
    wprep_kernel<<<32, 256, 0, stream>>>(qkv_w, proj_w, Wf, Pf);
    qkv_kernel<<<512, 256, 0, stream>>>(x, stats, norm_w, norm_b, Wf, qkv_b, Qf, Kf, Vf);
    attn_kernel<<<512, 256, 0, stream>>>(Qf, Kf, Vf, Opart, lsum);
    combine_kernel<<<1024, 256, 0, stream>>>(Opart, lsum, ao);
    proj_kernel<<<256, 256, 0, stream>>>(ao, Pf, proj_b, x, out);
}

// Round 9
// 140.964 us; speedup vs baseline: 6.9502x; 1.0466x over previous
//
#include <hip/hip_runtime.h>

typedef unsigned short u16;
typedef unsigned int   u32;

#define HW 4096
#define NC 128

typedef __bf16 bf16x8 __attribute__((ext_vector_type(8)));
typedef float  f32x16 __attribute__((ext_vector_type(16)));

__device__ __forceinline__ bf16x8 as_bf8(uint4 u){
    union { uint4 u; bf16x8 b; } c; c.u = u; return c.b;
}
__device__ __forceinline__ u16 f2bf(float f){
    u32 u = __float_as_uint(f);
    return (u16)((u + 0x7fffu + ((u >> 16) & 1u)) >> 16);
}
__device__ __forceinline__ u32 pack2(float a, float b){
    return ((__float_as_uint(a) + 0x8000u) >> 16) | ((__float_as_uint(b) + 0x8000u) & 0xffff0000u);
}
__device__ __forceinline__ float bf_lo(u32 u){ return __uint_as_float(u << 16); }
__device__ __forceinline__ float bf_hi(u32 u){ return __uint_as_float(u & 0xffff0000u); }
__device__ __forceinline__ void unpack8(uint4 u, float* v){
    v[0]=bf_lo(u.x); v[1]=bf_hi(u.x); v[2]=bf_lo(u.y); v[3]=bf_hi(u.y);
    v[4]=bf_lo(u.z); v[5]=bf_hi(u.z); v[6]=bf_lo(u.w); v[7]=bf_hi(u.w);
}

// async global -> LDS, 16B per lane
#define GLOAD_LDS16(g, l) \
    __builtin_amdgcn_global_load_lds((const __attribute__((address_space(1))) u32*)(const void*)(g), \
                                     (__attribute__((address_space(3))) u32*)(void*)(l), 16, 0, 0)

// ---------------- K1: fused GroupNorm partial sums + weight prep ----------------
// blocks 0..255: gn partials (stats[bg*16+part*2] = sum, +1 = sumsq).
// blocks 256..287: pack qkv_w -> Wf (6144 frags), proj_w -> Pf (2048 frags).
__global__ __launch_bounds__(256) void gnw_kernel(const float* __restrict__ x,
                                                  float* __restrict__ stats,
                                                  const float* __restrict__ qkv_w,
                                                  const float* __restrict__ proj_w,
                                                  uint4* __restrict__ Wf,
                                                  uint4* __restrict__ Pf){
    if (blockIdx.x < 256){
        int bg = blockIdx.x >> 3, part = blockIdx.x & 7;
        const float4* p = (const float4*)(x + (size_t)bg * 65536 + part * 8192);
        float s = 0.f, ss = 0.f;
        #pragma unroll
        for (int i = 0; i < 8; i++){
            float4 u = p[threadIdx.x + i*256];
            s  += u.x + u.y + u.z + u.w;
            ss += u.x*u.x + u.y*u.y + u.z*u.z + u.w*u.w;
        }
        #pragma unroll
        for (int off = 32; off > 0; off >>= 1){
            s  += __shfl_xor(s,  off);
            ss += __shfl_xor(ss, off);
        }
        __shared__ float rs[4], rss[4];
        int wid = threadIdx.x >> 6;
        if ((threadIdx.x & 63) == 0){ rs[wid] = s; rss[wid] = ss; }
        __syncthreads();
        if (threadIdx.x == 0){
            stats[bg*16 + part*2]     = rs[0]+rs[1]+rs[2]+rs[3];
            stats[bg*16 + part*2 + 1] = rss[0]+rss[1]+rss[2]+rss[3];
        }
    } else {
        int id = (blockIdx.x - 256)*256 + threadIdx.x;   // 0..8191
        const float* src; uint4* dst; int fi;
        if (id < 6144){ src = qkv_w; dst = Wf; fi = id; }
        else          { src = proj_w; dst = Pf; fi = id - 6144; }
        int l = fi & 63, ks = (fi >> 6) & 7, ob = fi >> 9;
        int o = ob*32 + (l & 31);
        int c = ks*16 + ((l >> 5) << 3);
        const float* s = src + o*128 + c;
        dst[fi] = make_uint4(pack2(s[0],s[1]), pack2(s[2],s[3]), pack2(s[4],s[5]), pack2(s[6],s[7]));
    }
}

// ---------------- K2: MFMA GN+QKV. grid 512 (b = x>>7, tokblk = x&127), block 256 ----------------
// wave wv handles obs {wv*3, wv*3+1, wv*3+2}; obs 0-3 -> Q, 4-7 -> K, 8-11 -> V.
__global__ __launch_bounds__(256) void qkv_kernel(const float* __restrict__ x,
                                                  const float* __restrict__ stats,
                                                  const float* __restrict__ gamma,
                                                  const float* __restrict__ beta,
                                                  const uint4* __restrict__ Wf,
                                                  const float* __restrict__ bias,
                                                  uint4* __restrict__ Qf,
                                                  uint4* __restrict__ Kf,
                                                  uint4* __restrict__ Vf){
    __shared__ float gaL[128], beL[128], biasL[384];
    int b = blockIdx.x >> 7, tokblk = blockIdx.x & 127;
    int t = threadIdx.x, lane = t & 63, wv = t >> 6;
    if (t < 128){
        int g = t >> 4;
        float S = 0.f, SS = 0.f;
        #pragma unroll
        for (int p = 0; p < 8; p++){
            S  += stats[(b*8 + g)*16 + p*2];
            SS += stats[(b*8 + g)*16 + p*2 + 1];
        }
        float mean = S * (1.f/65536.f);
        float rstd = rsqrtf(SS * (1.f/65536.f) - mean*mean + 1e-5f);
        float ga = gamma[t] * rstd;
        gaL[t] = ga; beL[t] = beta[t] - mean*ga;
    }
    if (t < 192){ biasL[t] = bias[t]; biasL[t+192] = bias[t+192]; }
    __syncthreads();

    int h = lane >> 5, tl = lane & 31;
    uint4 xf[8];
    const float* xb = x + (size_t)b*128*HW + tokblk*32 + tl;
    #pragma unroll
    for (int ks = 0; ks < 8; ks++){
        int c0 = ks*16 + h*8;
        float4 g0 = *(float4*)&gaL[c0], g1 = *(float4*)&gaL[c0+4];
        float4 e0 = *(float4*)&beL[c0], e1 = *(float4*)&beL[c0+4];
        float v[8];
        #pragma unroll
        for (int j = 0; j < 8; j++) v[j] = xb[(size_t)(c0+j)*HW];
        v[0] = fmaf(v[0], g0.x, e0.x); v[1] = fmaf(v[1], g0.y, e0.y);
        v[2] = fmaf(v[2], g0.z, e0.z); v[3] = fmaf(v[3], g0.w, e0.w);
        v[4] = fmaf(v[4], g1.x, e1.x); v[5] = fmaf(v[5], g1.y, e1.y);
        v[6] = fmaf(v[6], g1.z, e1.z); v[7] = fmaf(v[7], g1.w, e1.w);
        xf[ks] = make_uint4(pack2(v[0],v[1]), pack2(v[2],v[3]), pack2(v[4],v[5]), pack2(v[6],v[7]));
    }

    bool up = (lane >= 32);
    #pragma unroll
    for (int i = 0; i < 3; i++){
        int ob = wv*3 + i;
        uint4 wf[8];
        #pragma unroll
        for (int ks = 0; ks < 8; ks++) wf[ks] = Wf[(ob*8 + ks)*64 + lane];
        f32x16 D;
        #pragma unroll
        for (int r = 0; r < 16; r++) D[r] = 0.f;
        if (ob < 8){
            #pragma unroll
            for (int ks = 0; ks < 8; ks++)
                D = __builtin_amdgcn_mfma_f32_32x32x16_bf16(as_bf8(wf[ks]), as_bf8(xf[ks]), D, 0,0,0);
            #pragma unroll
            for (int r = 0; r < 16; r++)
                D[r] += biasL[ob*32 + (r&3) + 8*(r>>2) + 4*h];
            u32 pk[8], xch[8];
            #pragma unroll
            for (int j = 0; j < 8; j++) pk[j] = pack2(D[2*j], D[2*j+1]);
            #pragma unroll
            for (int j = 0; j < 8; j++) xch[j] = __shfl_xor(pk[j], 32);
            uint4 F0 = up ? make_uint4(xch[2],xch[3],pk[2],pk[3]) : make_uint4(pk[0],pk[1],xch[0],xch[1]);
            uint4 F1 = up ? make_uint4(xch[6],xch[7],pk[6],pk[7]) : make_uint4(pk[4],pk[5],xch[4],xch[5]);
            uint4* dst = (ob < 4) ? Qf : Kf;
            int obl = ob & 3;
            size_t base = (((size_t)b*128 + tokblk)*8 + obl*2)*64 + lane;
            dst[base] = F0; dst[base + 64] = F1;
        } else {
            #pragma unroll
            for (int ks = 0; ks < 8; ks++)
                D = __builtin_amdgcn_mfma_f32_32x32x16_bf16(as_bf8(xf[ks]), as_bf8(wf[ks]), D, 0,0,0);
            int nb = ob - 8;
            float vb = biasL[256 + nb*32 + tl];
            #pragma unroll
            for (int r = 0; r < 16; r++) D[r] += vb;
            u32 pk[8], xch[8];
            #pragma unroll
            for (int j = 0; j < 8; j++) pk[j] = pack2(D[2*j], D[2*j+1]);
            #pragma unroll
            for (int j = 0; j < 8; j++) xch[j] = __shfl_xor(pk[j], 32);
            uint4 F0 = up ? make_uint4(xch[2],xch[3],pk[2],pk[3]) : make_uint4(pk[0],pk[1],xch[0],xch[1]);
            uint4 F1 = up ? make_uint4(xch[6],xch[7],pk[6],pk[7]) : make_uint4(pk[4],pk[5],xch[4],xch[5]);
            int it = tokblk >> 1, t2 = tokblk & 1;
            size_t base = ((((size_t)b*64 + it)*4 + nb)*4 + t2*2)*64 + lane;
            Vf[base] = F0; Vf[base + 64] = F1;
        }
    }
}

// ---------------- K3: MFMA flash attention, wave = (q-half, k-half) ----------------
// grid 512, block 256. K: DMA -> LDS dbuf (32 KB). V: direct fragment loads from L2.
__global__ __launch_bounds__(256, 2) void attn_kernel(const uint4* __restrict__ Qf,
                                                      const uint4* __restrict__ Kf,
                                                      const uint4* __restrict__ Vf,
                                                      u16* __restrict__ Opart,
                                                      float* __restrict__ lsum){
    __shared__ uint4 smem[2048];   // K dbuf (32 KB)
    __shared__ float lred[64];
    int pair = blockIdx.x & 7, qx = blockIdx.x >> 3;
    int b = pair >> 1, ksp = pair & 1;
    int t = threadIdx.x, lane = t & 63, wv = t >> 6;
    int qh = wv >> 1, kh = wv & 1;
    const float SC = 0.08838834764831845f;   // 1/sqrt(128)

    uint4 qf[8];
    const uint4* qptr = Qf + ((size_t)b*128 + qx*2 + qh)*512 + lane;
    #pragma unroll
    for (int ks = 0; ks < 8; ks++) qf[ks] = qptr[ks*64];

    f32x16 O0, O1, O2, O3;
    #pragma unroll
    for (int r = 0; r < 16; r++){ O0[r]=0.f; O1[r]=0.f; O2[r]=0.f; O3[r]=0.f; }
    float l_i = 0.f;

    const uint4* kg = Kf + ((size_t)b*128 + ksp*64)*512;
    const uint4* vg = Vf + ((size_t)b*64  + ksp*32)*1024;

    #pragma unroll
    for (int i = 0; i < 4; i++)
        GLOAD_LDS16(kg + t + i*256, &smem[t + i*256]);
    __syncthreads();

    for (int it = 0; it < 32; it++){
        int cur = it & 1;
        if (it < 31){
            const uint4* kg2 = kg + (it+1)*1024;
            #pragma unroll
            for (int i = 0; i < 4; i++)
                GLOAD_LDS16(kg2 + t + i*256, &smem[(cur^1)*1024 + t + i*256]);
        }
        // V fragments for this wave's k-half: frag (nb*4 + kh*2 + ks), issued early
        const uint4* vgi = vg + it*1024 + lane;
        uint4 vf[8];
        #pragma unroll
        for (int nb = 0; nb < 4; nb++){
            vf[nb*2]   = vgi[(nb*4 + kh*2)     << 6];
            vf[nb*2+1] = vgi[(nb*4 + kh*2 + 1) << 6];
        }

        f32x16 S0;
        #pragma unroll
        for (int r = 0; r < 16; r++) S0[r] = 0.f;
        #pragma unroll
        for (int ks = 0; ks < 8; ks++)
            S0 = __builtin_amdgcn_mfma_f32_32x32x16_bf16(
                     as_bf8(smem[cur*1024 + ((kh*8 + ks)<<6) + lane]),
                     as_bf8(qf[ks]), S0, 0,0,0);

        float psum = 0.f;
        u32 pk[8];
        #pragma unroll
        for (int q = 0; q < 4; q++){
            float e0 = __expf(__fmaf_rn(S0[q*4+0], SC, -8.f));
            float e1 = __expf(__fmaf_rn(S0[q*4+1], SC, -8.f));
            float e2 = __expf(__fmaf_rn(S0[q*4+2], SC, -8.f));
            float e3 = __expf(__fmaf_rn(S0[q*4+3], SC, -8.f));
            psum += (e0+e1)+(e2+e3);
            pk[2*q] = pack2(e0,e1); pk[2*q+1] = pack2(e2,e3);
        }
        psum += __shfl_xor(psum, 32);
        l_i += psum;

        u32 xch[8];
        #pragma unroll
        for (int i = 0; i < 8; i++) xch[i] = __shfl_xor(pk[i], 32);
        bool up = (lane >= 32);
        uint4 fr0 = up ? make_uint4(xch[2],xch[3],pk[2],pk[3]) : make_uint4(pk[0],pk[1],xch[0],xch[1]);
        uint4 fr1 = up ? make_uint4(xch[6],xch[7],pk[6],pk[7]) : make_uint4(pk[4],pk[5],xch[4],xch[5]);

        #pragma unroll
        for (int ks = 0; ks < 2; ks++){
            bf16x8 pa = as_bf8(ks ? fr1 : fr0);
            O0 = __builtin_amdgcn_mfma_f32_32x32x16_bf16(pa, as_bf8(vf[0*2+ks]), O0, 0,0,0);
            O1 = __builtin_amdgcn_mfma_f32_32x32x16_bf16(pa, as_bf8(vf[1*2+ks]), O1, 0,0,0);
            O2 = __builtin_amdgcn_mfma_f32_32x32x16_bf16(pa, as_bf8(vf[2*2+ks]), O2, 0,0,0);
            O3 = __builtin_amdgcn_mfma_f32_32x32x16_bf16(pa, as_bf8(vf[3*2+ks]), O3, 0,0,0);
        }
        __syncthreads();   // next K tile's DMA drained; this tile's reads done
    }

    float* fsm = (float*)smem;     // 8192 floats = 32 KB, exactly fits
    if (kh == 1){
        #pragma unroll
        for (int r = 0; r < 16; r++){
            fsm[((qh*4+0)*16 + r)*64 + lane] = O0[r];
            fsm[((qh*4+1)*16 + r)*64 + lane] = O1[r];
            fsm[((qh*4+2)*16 + r)*64 + lane] = O2[r];
            fsm[((qh*4+3)*16 + r)*64 + lane] = O3[r];
        }
        if (lane < 32) lred[qh*32 + lane] = l_i;
    }
    __syncthreads();
    if (kh == 0){
        float lt = l_i + lred[qh*32 + (lane & 31)];
        if (lane < 32) lsum[((size_t)(ksp*4 + b))*HW + qx*64 + qh*32 + lane] = lt;
        u16* ob = Opart + (((size_t)(ksp*4 + b))*HW + qx*64 + qh*32)*NC;
        #pragma unroll
        for (int r = 0; r < 16; r++){
            int qr = (r&3) + 8*(r>>2) + 4*(lane>>5);
            int c  = lane & 31;
            ob[qr*NC +      c] = f2bf(O0[r] + fsm[((qh*4+0)*16 + r)*64 + lane]);
            ob[qr*NC + 32 + c] = f2bf(O1[r] + fsm[((qh*4+1)*16 + r)*64 + lane]);
            ob[qr*NC + 64 + c] = f2bf(O2[r] + fsm[((qh*4+2)*16 + r)*64 + lane]);
            ob[qr*NC + 96 + c] = f2bf(O3[r] + fsm[((qh*4+3)*16 + r)*64 + lane]);
        }
    }
}

// ---------------- K4: MFMA proj + inline K-split combine + bias + residual ----------------
// grid 256, block 256. ao B-fragments built in-register from the two Opart chunks.
__global__ __launch_bounds__(256) void proj_kernel(const u16* __restrict__ Op,
                                                   const float* __restrict__ lsum,
                                                   const uint4* __restrict__ Pf,
                                                   const float* __restrict__ bias,
                                                   const float* __restrict__ x,
                                                   float* __restrict__ out){
    __shared__ float biasL[128];
    int t = threadIdx.x, lane = t & 63, wv = t >> 6;
    if (t < 128) biasL[t] = bias[t];
    __syncthreads();
    int b = blockIdx.x >> 6, tk = blockIdx.x & 63;
    int tokb2 = wv & 1, obh = wv >> 1;
    int tokblk = tk*2 + tokb2;
    int h = lane >> 5, tl = lane & 31;

    int rowg = b*HW + tokblk*32 + tl;
    float inv = 1.f / (lsum[rowg] + lsum[16384 + rowg]);
    const u16* p0 = Op + (size_t)rowg*NC + h*8;
    uint4 af[8];
    #pragma unroll
    for (int ks = 0; ks < 8; ks++){
        uint4 u0 = *(const uint4*)(p0 + ks*16);
        uint4 u1 = *(const uint4*)(p0 + 2097152 + ks*16);
        float v0[8], v1[8];
        unpack8(u0, v0); unpack8(u1, v1);
        u32 q[4];
        #pragma unroll
        for (int j = 0; j < 4; j++)
            q[j] = pack2((v0[2*j] + v1[2*j]) * inv, (v0[2*j+1] + v1[2*j+1]) * inv);
        af[ks] = make_uint4(q[0], q[1], q[2], q[3]);
    }

    #pragma unroll
    for (int i = 0; i < 2; i++){
        int ob = obh*2 + i;
        uint4 pf[8];
        #pragma unroll
        for (int ks = 0; ks < 8; ks++) pf[ks] = Pf[(ob*8 + ks)*64 + lane];
        f32x16 D;
        #pragma unroll
        for (int r = 0; r < 16; r++) D[r] = 0.f;
        #pragma unroll
        for (int ks = 0; ks < 8; ks++)
            D = __builtin_amdgcn_mfma_f32_32x32x16_bf16(as_bf8(pf[ks]), as_bf8(af[ks]), D, 0,0,0);
        #pragma unroll
        for (int r = 0; r < 16; r++){
            int o = ob*32 + (r&3) + 8*(r>>2) + 4*h;
            size_t gi = ((size_t)b*128 + o)*HW + tokblk*32 + tl;
            out[gi] = x[gi] + biasL[o] + D[r];
        }
    }
}

extern "C" void kernel_launch(void* const* d_in, const int* in_sizes, int n_in,
                              void* d_out, int out_size, void* d_ws, size_t ws_size,
                              hipStream_t stream){
    const float* x      = (const float*)d_in[0];
    const float* norm_w = (const float*)d_in[1];
    const float* norm_b = (const float*)d_in[2];
    const float* qkv_w  = (const float*)d_in[3];
    const float* qkv_b  = (const float*)d_in[4];
    const float* proj_w = (const float*)d_in[5];
    const float* proj_b = (const float*)d_in[6];
    float* out = (float*)d_out;

    // ws: stats 2KB | Qf 4.19MB | Kf 4.19MB | Vf 4.19MB | lsum 128KB | Wf 96KB | Pf 32KB (~12.85MB)
    char* w = (char*)d_ws;
    float* stats = (float*)w;
    uint4* Qf = (uint4*)(w + 2048);
    uint4* Kf = (uint4*)(w + 2048 + 4194304);
    uint4* Vf = (uint4*)(w + 2048 + 8388608);
    float* lsum = (float*)(w + 2048 + 12582912);
    uint4* Wf = (uint4*)(w + 2048 + 12582912 + 131072);
    uint4* Pf = (uint4*)(w + 2048 + 12582912 + 131072 + 98304);
    u16* Opart = (u16*)d_out;     // 2 bf16 partial chunks = exactly 8.39 MB = d_out

    gnw_kernel<<<288, 256, 0, stream>>>(x, stats, qkv_w, proj_w, Wf, Pf);
    qkv_kernel<<<512, 256, 0, stream>>>(x, stats, norm_w, norm_b, Wf, qkv_b, Qf, Kf, Vf);
    attn_kernel<<<512, 256, 0, stream>>>(Qf, Kf, Vf, Opart, lsum);
    proj_kernel<<<256, 256, 0, stream>>>(Opart, lsum, Pf, proj_b, x, out);
}

// Round 11
// 135.257 us; speedup vs baseline: 7.2435x; 1.0422x over previous
//
#include <hip/hip_runtime.h>

typedef unsigned short u16;
typedef unsigned int   u32;

#define HW 4096
#define NC 128

typedef __bf16 bf16x8 __attribute__((ext_vector_type(8)));
typedef float  f32x16 __attribute__((ext_vector_type(16)));

__device__ __forceinline__ bf16x8 as_bf8(uint4 u){
    union { uint4 u; bf16x8 b; } c; c.u = u; return c.b;
}
__device__ __forceinline__ u16 f2bf(float f){
    u32 u = __float_as_uint(f);
    return (u16)((u + 0x7fffu + ((u >> 16) & 1u)) >> 16);
}
__device__ __forceinline__ u32 pack2(float a, float b){
    return ((__float_as_uint(a) + 0x8000u) >> 16) | ((__float_as_uint(b) + 0x8000u) & 0xffff0000u);
}
__device__ __forceinline__ float bf_lo(u32 u){ return __uint_as_float(u << 16); }
__device__ __forceinline__ float bf_hi(u32 u){ return __uint_as_float(u & 0xffff0000u); }
__device__ __forceinline__ void unpack8(uint4 u, float* v){
    v[0]=bf_lo(u.x); v[1]=bf_hi(u.x); v[2]=bf_lo(u.y); v[3]=bf_hi(u.y);
    v[4]=bf_lo(u.z); v[5]=bf_hi(u.z); v[6]=bf_lo(u.w); v[7]=bf_hi(u.w);
}

// 2^x via the HW transcendental unit (avoid glibc __exp2f macro collision)
__device__ __forceinline__ float exp2_hw(float x){ return __builtin_amdgcn_exp2f(x); }

// ---------------- K1: fused GroupNorm partial sums + weight prep ----------------
__global__ __launch_bounds__(256) void gnw_kernel(const float* __restrict__ x,
                                                  float* __restrict__ stats,
                                                  const float* __restrict__ qkv_w,
                                                  const float* __restrict__ proj_w,
                                                  uint4* __restrict__ Wf,
                                                  uint4* __restrict__ Pf){
    if (blockIdx.x < 256){
        int bg = blockIdx.x >> 3, part = blockIdx.x & 7;
        const float4* p = (const float4*)(x + (size_t)bg * 65536 + part * 8192);
        float s = 0.f, ss = 0.f;
        #pragma unroll
        for (int i = 0; i < 8; i++){
            float4 u = p[threadIdx.x + i*256];
            s  += u.x + u.y + u.z + u.w;
            ss += u.x*u.x + u.y*u.y + u.z*u.z + u.w*u.w;
        }
        #pragma unroll
        for (int off = 32; off > 0; off >>= 1){
            s  += __shfl_xor(s,  off);
            ss += __shfl_xor(ss, off);
        }
        __shared__ float rs[4], rss[4];
        int wid = threadIdx.x >> 6;
        if ((threadIdx.x & 63) == 0){ rs[wid] = s; rss[wid] = ss; }
        __syncthreads();
        if (threadIdx.x == 0){
            stats[bg*16 + part*2]     = rs[0]+rs[1]+rs[2]+rs[3];
            stats[bg*16 + part*2 + 1] = rss[0]+rss[1]+rss[2]+rss[3];
        }
    } else {
        int id = (blockIdx.x - 256)*256 + threadIdx.x;   // 0..8191
        const float* src; uint4* dst; int fi;
        if (id < 6144){ src = qkv_w; dst = Wf; fi = id; }
        else          { src = proj_w; dst = Pf; fi = id - 6144; }
        int l = fi & 63, ks = (fi >> 6) & 7, ob = fi >> 9;
        int o = ob*32 + (l & 31);
        int c = ks*16 + ((l >> 5) << 3);
        const float* s = src + o*128 + c;
        dst[fi] = make_uint4(pack2(s[0],s[1]), pack2(s[2],s[3]), pack2(s[4],s[5]), pack2(s[6],s[7]));
    }
}

// ---------------- K2: MFMA GN+QKV. grid 512 (b = x>>7, tokblk = x&127), block 256 ----------------
__global__ __launch_bounds__(256) void qkv_kernel(const float* __restrict__ x,
                                                  const float* __restrict__ stats,
                                                  const float* __restrict__ gamma,
                                                  const float* __restrict__ beta,
                                                  const uint4* __restrict__ Wf,
                                                  const float* __restrict__ bias,
                                                  uint4* __restrict__ Qf,
                                                  uint4* __restrict__ Kf,
                                                  uint4* __restrict__ Vf){
    __shared__ float gaL[128], beL[128], biasL[384];
    int b = blockIdx.x >> 7, tokblk = blockIdx.x & 127;
    int t = threadIdx.x, lane = t & 63, wv = t >> 6;
    if (t < 128){
        int g = t >> 4;
        float S = 0.f, SS = 0.f;
        #pragma unroll
        for (int p = 0; p < 8; p++){
            S  += stats[(b*8 + g)*16 + p*2];
            SS += stats[(b*8 + g)*16 + p*2 + 1];
        }
        float mean = S * (1.f/65536.f);
        float rstd = rsqrtf(SS * (1.f/65536.f) - mean*mean + 1e-5f);
        float ga = gamma[t] * rstd;
        gaL[t] = ga; beL[t] = beta[t] - mean*ga;
    }
    if (t < 192){ biasL[t] = bias[t]; biasL[t+192] = bias[t+192]; }
    __syncthreads();

    int h = lane >> 5, tl = lane & 31;
    uint4 xf[8];
    const float* xb = x + (size_t)b*128*HW + tokblk*32 + tl;
    #pragma unroll
    for (int ks = 0; ks < 8; ks++){
        int c0 = ks*16 + h*8;
        float4 g0 = *(float4*)&gaL[c0], g1 = *(float4*)&gaL[c0+4];
        float4 e0 = *(float4*)&beL[c0], e1 = *(float4*)&beL[c0+4];
        float v[8];
        #pragma unroll
        for (int j = 0; j < 8; j++) v[j] = xb[(size_t)(c0+j)*HW];
        v[0] = fmaf(v[0], g0.x, e0.x); v[1] = fmaf(v[1], g0.y, e0.y);
        v[2] = fmaf(v[2], g0.z, e0.z); v[3] = fmaf(v[3], g0.w, e0.w);
        v[4] = fmaf(v[4], g1.x, e1.x); v[5] = fmaf(v[5], g1.y, e1.y);
        v[6] = fmaf(v[6], g1.z, e1.z); v[7] = fmaf(v[7], g1.w, e1.w);
        xf[ks] = make_uint4(pack2(v[0],v[1]), pack2(v[2],v[3]), pack2(v[4],v[5]), pack2(v[6],v[7]));
    }

    bool up = (lane >= 32);
    #pragma unroll
    for (int i = 0; i < 3; i++){
        int ob = wv*3 + i;
        uint4 wf[8];
        #pragma unroll
        for (int ks = 0; ks < 8; ks++) wf[ks] = Wf[(ob*8 + ks)*64 + lane];
        f32x16 D;
        #pragma unroll
        for (int r = 0; r < 16; r++) D[r] = 0.f;
        if (ob < 8){
            #pragma unroll
            for (int ks = 0; ks < 8; ks++)
                D = __builtin_amdgcn_mfma_f32_32x32x16_bf16(as_bf8(wf[ks]), as_bf8(xf[ks]), D, 0,0,0);
            #pragma unroll
            for (int r = 0; r < 16; r++)
                D[r] += biasL[ob*32 + (r&3) + 8*(r>>2) + 4*h];
            u32 pk[8], xch[8];
            #pragma unroll
            for (int j = 0; j < 8; j++) pk[j] = pack2(D[2*j], D[2*j+1]);
            #pragma unroll
            for (int j = 0; j < 8; j++) xch[j] = __shfl_xor(pk[j], 32);
            uint4 F0 = up ? make_uint4(xch[2],xch[3],pk[2],pk[3]) : make_uint4(pk[0],pk[1],xch[0],xch[1]);
            uint4 F1 = up ? make_uint4(xch[6],xch[7],pk[6],pk[7]) : make_uint4(pk[4],pk[5],xch[4],xch[5]);
            uint4* dst = (ob < 4) ? Qf : Kf;
            int obl = ob & 3;
            size_t base = (((size_t)b*128 + tokblk)*8 + obl*2)*64 + lane;
            dst[base] = F0; dst[base + 64] = F1;
        } else {
            #pragma unroll
            for (int ks = 0; ks < 8; ks++)
                D = __builtin_amdgcn_mfma_f32_32x32x16_bf16(as_bf8(xf[ks]), as_bf8(wf[ks]), D, 0,0,0);
            int nb = ob - 8;
            float vb = biasL[256 + nb*32 + tl];
            #pragma unroll
            for (int r = 0; r < 16; r++) D[r] += vb;
            u32 pk[8], xch[8];
            #pragma unroll
            for (int j = 0; j < 8; j++) pk[j] = pack2(D[2*j], D[2*j+1]);
            #pragma unroll
            for (int j = 0; j < 8; j++) xch[j] = __shfl_xor(pk[j], 32);
            uint4 F0 = up ? make_uint4(xch[2],xch[3],pk[2],pk[3]) : make_uint4(pk[0],pk[1],xch[0],xch[1]);
            uint4 F1 = up ? make_uint4(xch[6],xch[7],pk[6],pk[7]) : make_uint4(pk[4],pk[5],xch[4],xch[5]);
            int it = tokblk >> 1, t2 = tokblk & 1;
            size_t base = ((((size_t)b*64 + it)*4 + nb)*4 + t2*2)*64 + lane;
            Vf[base] = F0; Vf[base + 64] = F1;
        }
    }
}

// ---------------- K3: MFMA flash attention, barrier-free K-loop ----------------
// grid 512 (pair = blockIdx.x&7 -> (b,ksp); qx = blockIdx.x>>3), block 256 = 4 waves (qh,kh).
// K and V both direct per-wave fragment loads from L2 (coalesced 1KB per instr).
// Single end barrier for cross-kh reduce; epilogue emits B-fragment-order Opart.
__global__ __launch_bounds__(256, 2) void attn_kernel(const uint4* __restrict__ Qf,
                                                      const uint4* __restrict__ Kf,
                                                      const uint4* __restrict__ Vf,
                                                      uint4* __restrict__ Opart,
                                                      float* __restrict__ lsum){
    __shared__ float fsm[8192];    // 32 KB: kh=1 O hand-off
    __shared__ float lred[64];
    int pair = blockIdx.x & 7, qx = blockIdx.x >> 3;
    int b = pair >> 1, ksp = pair & 1;
    int t = threadIdx.x, lane = t & 63, wv = t >> 6;
    int qh = wv >> 1, kh = wv & 1;
    const float SC2 = 0.12751744361402804f;   // (1/sqrt(128))*log2(e)
    const float B2  = -11.541560327111707f;   // -8*log2(e)

    uint4 qf[8];
    const uint4* qptr = Qf + (((size_t)b*128 + qx*2 + qh)*8)*64 + lane;
    #pragma unroll
    for (int ks = 0; ks < 8; ks++) qf[ks] = qptr[ks*64];

    f32x16 O[4];
    #pragma unroll
    for (int nb = 0; nb < 4; nb++)
        #pragma unroll
        for (int r = 0; r < 16; r++) O[nb][r] = 0.f;
    float l_i = 0.f;

    // per-wave fragment streams
    const uint4* kgw = Kf + (((size_t)b*128 + ksp*64)*8)*64 + (kh<<9) + lane;
    const uint4* vgw = Vf + (((size_t)b*64  + ksp*32)*16)*64 + (kh<<7) + lane;

    uint4 kf[8], vf[8];
    #pragma unroll
    for (int ks = 0; ks < 8; ks++) kf[ks] = kgw[ks*64];
    #pragma unroll
    for (int nb = 0; nb < 4; nb++){
        vf[nb*2]   = vgw[nb*256];
        vf[nb*2+1] = vgw[nb*256 + 64];
    }

    for (int it = 0; it < 32; it++){
        // S' = K·Q^T (this wave's 32 kt): split chain for ILP
        f32x16 Sa, Sb;
        #pragma unroll
        for (int r = 0; r < 16; r++){ Sa[r] = 0.f; Sb[r] = 0.f; }
        #pragma unroll
        for (int ks = 0; ks < 4; ks++)
            Sa = __builtin_amdgcn_mfma_f32_32x32x16_bf16(as_bf8(kf[ks]), as_bf8(qf[ks]), Sa, 0,0,0);
        #pragma unroll
        for (int ks = 4; ks < 8; ks++)
            Sb = __builtin_amdgcn_mfma_f32_32x32x16_bf16(as_bf8(kf[ks]), as_bf8(qf[ks]), Sb, 0,0,0);
        #pragma unroll
        for (int r = 0; r < 16; r++) Sa[r] += Sb[r];

        // prefetch next K frags (regs free after the chains above)
        if (it < 31){
            const uint4* kn = kgw + (it+1)*1024;
            #pragma unroll
            for (int ks = 0; ks < 8; ks++) kf[ks] = kn[ks*64];
        }

        // softmax: e = 2^(S*SC2 + B2) == exp(S*SC - 8)
        float psum = 0.f;
        u32 pk[8];
        #pragma unroll
        for (int q = 0; q < 4; q++){
            float e0 = exp2_hw(__fmaf_rn(Sa[q*4+0], SC2, B2));
            float e1 = exp2_hw(__fmaf_rn(Sa[q*4+1], SC2, B2));
            float e2 = exp2_hw(__fmaf_rn(Sa[q*4+2], SC2, B2));
            float e3 = exp2_hw(__fmaf_rn(Sa[q*4+3], SC2, B2));
            psum += (e0+e1)+(e2+e3);
            pk[2*q] = pack2(e0,e1); pk[2*q+1] = pack2(e2,e3);
        }
        psum += __shfl_xor(psum, 32);
        l_i += psum;

        u32 xch[8];
        #pragma unroll
        for (int i = 0; i < 8; i++) xch[i] = __shfl_xor(pk[i], 32);
        bool up = (lane >= 32);
        uint4 fr0 = up ? make_uint4(xch[2],xch[3],pk[2],pk[3]) : make_uint4(pk[0],pk[1],xch[0],xch[1]);
        uint4 fr1 = up ? make_uint4(xch[6],xch[7],pk[6],pk[7]) : make_uint4(pk[4],pk[5],xch[4],xch[5]);

        // PV, operands swapped: O^T[ch][qr] = V^T · P^T  (A=vf, B=fr)
        #pragma unroll
        for (int nb = 0; nb < 4; nb++){
            O[nb] = __builtin_amdgcn_mfma_f32_32x32x16_bf16(as_bf8(vf[nb*2]),   as_bf8(fr0), O[nb], 0,0,0);
            O[nb] = __builtin_amdgcn_mfma_f32_32x32x16_bf16(as_bf8(vf[nb*2+1]), as_bf8(fr1), O[nb], 0,0,0);
        }

        // prefetch next V frags
        if (it < 31){
            const uint4* vn = vgw + (it+1)*1024;
            #pragma unroll
            for (int nb = 0; nb < 4; nb++){
                vf[nb*2]   = vn[nb*256];
                vf[nb*2+1] = vn[nb*256 + 64];
            }
        }
    }

    // cross-kh reduce
    if (kh == 1){
        #pragma unroll
        for (int nb = 0; nb < 4; nb++)
            #pragma unroll
            for (int r = 0; r < 16; r++)
                fsm[((qh*4+nb)*16 + r)*64 + lane] = O[nb][r];
        if (lane < 32) lred[qh*32 + lane] = l_i;
    }
    __syncthreads();
    if (kh == 0){
        float lt = l_i + lred[qh*32 + (lane & 31)];
        if (lane < 32) lsum[((size_t)(ksp*4 + b))*HW + (qx*2+qh)*32 + lane] = lt;
        bool up = (lane >= 32);
        uint4* oc = Opart + (size_t)ksp*262144 + (((size_t)b*128 + qx*2 + qh)*8)*64 + lane;
        #pragma unroll
        for (int nb = 0; nb < 4; nb++){
            #pragma unroll
            for (int r = 0; r < 16; r++) O[nb][r] += fsm[((qh*4+nb)*16 + r)*64 + lane];
            u32 pk[8], xch[8];
            #pragma unroll
            for (int j = 0; j < 8; j++) pk[j] = pack2(O[nb][2*j], O[nb][2*j+1]);
            #pragma unroll
            for (int j = 0; j < 8; j++) xch[j] = __shfl_xor(pk[j], 32);
            uint4 F0 = up ? make_uint4(xch[2],xch[3],pk[2],pk[3]) : make_uint4(pk[0],pk[1],xch[0],xch[1]);
            uint4 F1 = up ? make_uint4(xch[6],xch[7],pk[6],pk[7]) : make_uint4(pk[4],pk[5],xch[4],xch[5]);
            oc[(nb*2)*64]     = F0;
            oc[(nb*2 + 1)*64] = F1;
        }
    }
}

// ---------------- K4: MFMA proj + inline combine + bias + residual ----------------
// grid 256, block 256. Opart chunks are B-fragment-ordered -> fully coalesced loads.
__global__ __launch_bounds__(256) void proj_kernel(const uint4* __restrict__ Op,
                                                   const float* __restrict__ lsum,
                                                   const uint4* __restrict__ Pf,
                                                   const float* __restrict__ bias,
                                                   const float* __restrict__ x,
                                                   float* __restrict__ out){
    __shared__ float biasL[128];
    int t = threadIdx.x, lane = t & 63, wv = t >> 6;
    if (t < 128) biasL[t] = bias[t];
    __syncthreads();
    int b = blockIdx.x >> 6, tk = blockIdx.x & 63;
    int tokb2 = wv & 1, obh = wv >> 1;
    int tokblk = tk*2 + tokb2;
    int h = lane >> 5, tl = lane & 31;

    int rowg = b*HW + tokblk*32 + tl;
    float inv = 1.f / (lsum[rowg] + lsum[16384 + rowg]);
    const uint4* c0p = Op + (((size_t)b*128 + tokblk)*8)*64 + lane;
    uint4 af[8];
    #pragma unroll
    for (int ks = 0; ks < 8; ks++){
        uint4 u0 = c0p[ks*64];
        uint4 u1 = c0p[262144 + ks*64];
        float v0[8], v1[8];
        unpack8(u0, v0); unpack8(u1, v1);
        u32 q[4];
        #pragma unroll
        for (int j = 0; j < 4; j++)
            q[j] = pack2((v0[2*j] + v1[2*j]) * inv, (v0[2*j+1] + v1[2*j+1]) * inv);
        af[ks] = make_uint4(q[0], q[1], q[2], q[3]);
    }

    #pragma unroll
    for (int i = 0; i < 2; i++){
        int ob = obh*2 + i;
        uint4 pf[8];
        #pragma unroll
        for (int ks = 0; ks < 8; ks++) pf[ks] = Pf[(ob*8 + ks)*64 + lane];
        f32x16 D;
        #pragma unroll
        for (int r = 0; r < 16; r++) D[r] = 0.f;
        #pragma unroll
        for (int ks = 0; ks < 8; ks++)
            D = __builtin_amdgcn_mfma_f32_32x32x16_bf16(as_bf8(pf[ks]), as_bf8(af[ks]), D, 0,0,0);
        #pragma unroll
        for (int r = 0; r < 16; r++){
            int o = ob*32 + (r&3) + 8*(r>>2) + 4*h;
            size_t gi = ((size_t)b*128 + o)*HW + tokblk*32 + tl;
            out[gi] = x[gi] + biasL[o] + D[r];
        }
    }
}

extern "C" void kernel_launch(void* const* d_in, const int* in_sizes, int n_in,
                              void* d_out, int out_size, void* d_ws, size_t ws_size,
                              hipStream_t stream){
    const float* x      = (const float*)d_in[0];
    const float* norm_w = (const float*)d_in[1];
    const float* norm_b = (const float*)d_in[2];
    const float* qkv_w  = (const float*)d_in[3];
    const float* qkv_b  = (const float*)d_in[4];
    const float* proj_w = (const float*)d_in[5];
    const float* proj_b = (const float*)d_in[6];
    float* out = (float*)d_out;

    // ws: stats 2KB | Qf 4.19MB | Kf 4.19MB | Vf 4.19MB | lsum 128KB | Wf 96KB | Pf 32KB (~12.85MB)
    char* w = (char*)d_ws;
    float* stats = (float*)w;
    uint4* Qf = (uint4*)(w + 2048);
    uint4* Kf = (uint4*)(w + 2048 + 4194304);
    uint4* Vf = (uint4*)(w + 2048 + 8388608);
    float* lsum = (float*)(w + 2048 + 12582912);
    uint4* Wf = (uint4*)(w + 2048 + 12582912 + 131072);
    uint4* Pf = (uint4*)(w + 2048 + 12582912 + 131072 + 98304);
    uint4* Opart = (uint4*)d_out;   // 2 fragment-ordered bf16 chunks = exactly 8.39 MB

    gnw_kernel<<<288, 256, 0, stream>>>(x, stats, qkv_w, proj_w, Wf, Pf);
    qkv_kernel<<<512, 256, 0, stream>>>(x, stats, norm_w, norm_b, Wf, qkv_b, Qf, Kf, Vf);
    attn_kernel<<<512, 256, 0, stream>>>(Qf, Kf, Vf, Opart, lsum);
    proj_kernel<<<256, 256, 0, stream>>>(Opart, lsum, Pf, proj_b, x, out);
}